// Round 4
// baseline (62212.067 us; speedup 1.0000x reference)
//
#include <hip/hip_runtime.h>
#include <math.h>

#define HD 1024
#define CD 256
#define TT 512
#define GD 4096                 // 4*H
#define NWG 256
#define NTH 1024
#define WPB (NTH/64)            // waves per block = 16
#define NWAVE (NWG*WPB)         // 4096
#define LAMF 0.05f

typedef unsigned long long ull;

// ---------------- persistent device scratch (re-initialized every call) ----
__device__ __align__(16) float d_g1[GD], d_g2[GD], d_g3[GD];
__device__ __align__(16) float d_BU0[HD], d_BU1[HD], d_BU2[HD];
__device__ __align__(16) float d_z1[CD];
__device__ __align__(16) float d_h1[2][HD], d_c1[2][HD], d_h2[2][HD], d_c2[2][HD], d_h3[2][HD], d_c3[2][HD];
__device__ __align__(16) float d_rec1[2][CD], d_rec2[2][HD], d_rec3[2][HD];
__device__ __align__(16) float d_TD1[2][HD], d_TD2[2][HD];
// one byte-flag per WG, packed into 4 cache lines; whole array polled at once
__device__ __align__(256) unsigned int d_flagw[NWG / 4];

__global__ void pc_init() { if (threadIdx.x < NWG / 4) d_flagw[threadIdx.x] = 0u; }

__device__ __forceinline__ float sigf(float x)     { return 1.f / (1.f + __expf(-x)); }
__device__ __forceinline__ float tanhfast(float x) { return 1.f - 2.f / (1.f + __expf(2.f * x)); }

// Coherent (cache-bypassing) accesses for cross-WG activation data. No
// cache-invalidating fences anywhere -> read-only weights stay hot in L1/L2.
__device__ __forceinline__ float cload(const float* p) {
  return __hip_atomic_load(p, __ATOMIC_RELAXED, __HIP_MEMORY_SCOPE_AGENT);
}
__device__ __forceinline__ void cstore(float* p, float v) {
  __hip_atomic_store(p, v, __ATOMIC_RELAXED, __HIP_MEMORY_SCOPE_AGENT);
}
__device__ __forceinline__ float2 cload2(const float* p) {
  union { ull u; float2 f; } c;
  c.u = __hip_atomic_load((const ull*)p, __ATOMIC_RELAXED, __HIP_MEMORY_SCOPE_AGENT);
  return c.f;
}
__device__ __forceinline__ void cstore2(float* p, float a, float b) {
  union { ull u; float2 f; } c;
  c.f = make_float2(a, b);
  __hip_atomic_store((ull*)p, c.u, __ATOMIC_RELAXED, __HIP_MEMORY_SCOPE_AGENT);
}

// Single-hop byte-epoch barrier: each WG release-stores (ep&0xFF) into its own
// byte; wave 0 of EVERY WG polls all 256 flags (64 lanes x u32) directly.
// Wrap-safe compare: flag is "arrived" iff (f - ep) mod 256 < 128 (max lead=1).
__device__ __forceinline__ void gbar(int& ep) {
  ++ep;
  __syncthreads();              // per-wave vmcnt drain (compiler) + WG sync
  if (threadIdx.x == 0)
    __hip_atomic_store((unsigned char*)d_flagw + blockIdx.x, (unsigned char)ep,
                       __ATOMIC_RELEASE, __HIP_MEMORY_SCOPE_AGENT);
  if (threadIdx.x < 64) {
    const unsigned char e8 = (unsigned char)ep;
    for (;;) {
      unsigned int v = __hip_atomic_load(d_flagw + threadIdx.x,
                                         __ATOMIC_RELAXED, __HIP_MEMORY_SCOPE_AGENT);
      bool ok = true;
      #pragma unroll
      for (int b = 0; b < 4; ++b) {
        unsigned char f = (unsigned char)(v >> (8 * b));
        ok = ok && ((unsigned char)(f - e8) < (unsigned char)128);
      }
      if (__all(ok)) break;
      __builtin_amdgcn_s_sleep(2);
    }
  }
  __syncthreads();
}

__device__ __forceinline__ float wredsum(float v) {
  #pragma unroll
  for (int off = 32; off; off >>= 1) v += __shfl_xor(v, off);
  return v;
}

__device__ __forceinline__ float bredsum(float v, float* sred) {
  __syncthreads();
  v = wredsum(v);
  if ((threadIdx.x & 63) == 0) sred[threadIdx.x >> 6] = v;
  __syncthreads();
  float r = (threadIdx.x < WPB) ? sred[threadIdx.x] : 0.f;
  r += __shfl_xor(r, 1); r += __shfl_xor(r, 2); r += __shfl_xor(r, 4); r += __shfl_xor(r, 8);
  if (threadIdx.x == 0) sred[0] = r;
  __syncthreads();
  return sred[0];
}

__device__ __forceinline__ float bredmax(float v, float* sred) {
  __syncthreads();
  #pragma unroll
  for (int off = 32; off; off >>= 1) v = fmaxf(v, __shfl_xor(v, off));
  if ((threadIdx.x & 63) == 0) sred[threadIdx.x >> 6] = v;
  __syncthreads();
  float r = (threadIdx.x < WPB) ? sred[threadIdx.x] : -INFINITY;
  r = fmaxf(r, __shfl_xor(r, 1)); r = fmaxf(r, __shfl_xor(r, 2));
  r = fmaxf(r, __shfl_xor(r, 4)); r = fmaxf(r, __shfl_xor(r, 8));
  if (threadIdx.x == 0) sred[0] = r;
  __syncthreads();
  return sred[0];
}

// prefetch NF4 float4 chunks of one weight row into registers (row len NF4*256 floats)
template<int NF4>
__device__ __forceinline__ void pf_row(const float* __restrict__ w, int lane, float4* pf) {
  #pragma unroll
  for (int i = 0; i < NF4; ++i) pf[i] = *(const float4*)(w + lane * 4 + i * 256);
}
// dot prefetched row chunks against an LDS vector
template<int NF4>
__device__ __forceinline__ float dot_pf(const float4* pf, const float* xv, int lane) {
  float a0 = 0.f, a1 = 0.f, a2 = 0.f, a3 = 0.f;
  #pragma unroll
  for (int i = 0; i < NF4; ++i) {
    const float4 vv = *(const float4*)(xv + lane * 4 + i * 256);
    a0 = fmaf(pf[i].x, vv.x, a0); a1 = fmaf(pf[i].y, vv.y, a1);
    a2 = fmaf(pf[i].z, vv.z, a2); a3 = fmaf(pf[i].w, vv.w, a3);
  }
  return (a0 + a1) + (a2 + a3);
}

__global__ __launch_bounds__(NTH, 4) void pc_main(
    const float* __restrict__ x,
    const float* __restrict__ Wih1, const float* __restrict__ Whh1,
    const float* __restrict__ bih1, const float* __restrict__ bhh1,
    const float* __restrict__ Vw1,  const float* __restrict__ Vb1,
    const float* __restrict__ Wih2, const float* __restrict__ Whh2,
    const float* __restrict__ bih2, const float* __restrict__ bhh2,
    const float* __restrict__ Vw2,  const float* __restrict__ Vb2,
    const float* __restrict__ Wih3, const float* __restrict__ Whh3,
    const float* __restrict__ bih3, const float* __restrict__ bhh3,
    const float* __restrict__ Vw3,  const float* __restrict__ Vb3,
    const float* __restrict__ Ww0,  const float* __restrict__ Wb0,
    const float* __restrict__ Ww1,  const float* __restrict__ Wb1,
    const float* __restrict__ Ww2,  const float* __restrict__ Wb2,
    const float* __restrict__ r1,   const float* __restrict__ r2,
    const float* __restrict__ r3,
    float* __restrict__ out) {
  const int tid  = threadIdx.x;
  const int lane = tid & 63;
  const int wid  = blockIdx.x * WPB + (tid >> 6);
  const bool iswg0 = (blockIdx.x == 0);

  __shared__ __align__(16) float s_x0[HD];
  __shared__ __align__(16) float s_x1[HD];
  __shared__ __align__(16) float s_x2[HD];
  __shared__ __align__(16) float s_aux[HD];
  __shared__ __align__(16) float s_small[CD];
  __shared__ float s_red[WPB];

  float4 pfA[8], pfB[4], pfC[4];
  float  pfbias = 0.f, pfbias2 = 0.f;
  int ep = 0;
  float loss_acc = 0.f, fll_acc = 0.f;

  // ---------------- Stage P: init state + BU0(0) + prefetch S1(0) ----------
  {
    float z = (tid < CD) ? r1[tid] : -INFINITY;
    float m = bredmax(z, s_red);
    float e = (tid < CD) ? __expf(z - m) : 0.f;
    float ssum = bredsum(e, s_red);
    if (tid < CD) {
      float p = e / ssum;               // rec1(0) = softmax(r1)
      s_small[tid] = x[tid] - p;        // TD0 at t=0
      if (iswg0) cstore(&d_rec1[0][tid], p);
    }
    if (iswg0) {
      for (int j = tid; j < HD; j += NTH) {
        cstore(&d_h1[0][j], 0.f); cstore(&d_c1[0][j], 0.f);
        cstore(&d_h2[0][j], 0.f); cstore(&d_c2[0][j], 0.f);
        cstore(&d_h3[0][j], 0.f); cstore(&d_c3[0][j], 0.f);
        cstore(&d_TD1[0][j], 0.f); cstore(&d_TD2[0][j], 0.f);
        cstore(&d_rec2[0][j], r2[j]); cstore(&d_rec3[0][j], r3[j]);
      }
    }
    __syncthreads();
    if (wid < HD) {
      const float4 w4 = *(const float4*)(Ww0 + (size_t)wid * CD + lane * 4);
      const float4 xv = *(const float4*)(s_small + lane * 4);
      float s = fmaf(w4.x, xv.x, fmaf(w4.y, xv.y, fmaf(w4.z, xv.z, w4.w * xv.w)));
      s = wredsum(s);
      if (lane == 0) cstore(&d_BU0[wid], s + Wb0[wid]);
    }
    pf_row<8>(Wih1 + (size_t)wid * (2 * HD), lane, pfA);
    pf_row<4>(Whh1 + (size_t)wid * HD, lane, pfB);
    pfbias = bih1[wid] + bhh1[wid];
  }
  gbar(ep);

  for (int t = 0; t < TT; ++t) {
    const int cur = t & 1, nxt = cur ^ 1;

    // ---- S1: g1 = Wih1@[BU0;TD1] + Whh1@h1 ; rec3 = Vw3@h3n (t>0) ----
    {
      if (tid < 512) {
        int j = tid * 2;
        float2 a = cload2(&d_BU0[j]);      *(float2*)(s_x0 + j) = a;
        float2 b = cload2(&d_TD1[cur][j]); *(float2*)(s_x1 + j) = b;
        float2 c = cload2(&d_h1[cur][j]);  *(float2*)(s_x2 + j) = c;
      }
      if (t > 0 && tid < 512) {
        int j = tid * 2;
        const int prv = nxt;              // (t-1)&1
        float2 gi = cload2(&d_g3[j]),        gf = cload2(&d_g3[j + HD]);
        float2 gg = cload2(&d_g3[j + 2*HD]), go = cload2(&d_g3[j + 3*HD]);
        float2 cp = cload2(&d_c3[prv][j]);
        float cA = sigf(gf.x) * cp.x + sigf(gi.x) * tanhfast(gg.x);
        float cB = sigf(gf.y) * cp.y + sigf(gi.y) * tanhfast(gg.y);
        float hA = sigf(go.x) * tanhfast(cA);
        float hB = sigf(go.y) * tanhfast(cB);
        s_aux[j] = hA; s_aux[j + 1] = hB;
        if (iswg0) { cstore2(&d_h3[cur][j], hA, hB); cstore2(&d_c3[cur][j], cA, cB); }
      }
      __syncthreads();
      {
        float s = dot_pf<4>(pfA, s_x0, lane) + dot_pf<4>(pfA + 4, s_x1, lane)
                + dot_pf<4>(pfB, s_x2, lane);
        s = wredsum(s);
        if (lane == 0) cstore(&d_g1[wid], s + pfbias);
      }
      if (t > 0 && wid < HD) {
        float s = dot_pf<4>(pfC, s_aux, lane);
        s = wredsum(s);
        if (lane == 0) cstore(&d_rec3[cur][wid], s + pfbias2);
      }
      // prefetch S2 rows
      if (wid < HD)            { pf_row<4>(Ww1 + (size_t)wid * HD, lane, pfB); pfbias = Wb1[wid]; }
      else if (wid < HD + CD)  { pf_row<4>(Vw1 + (size_t)(wid - HD) * HD, lane, pfB); pfbias = Vb1[wid - HD]; }
    }
    gbar(ep);

    // ---- S2: lstm1 cell ; BU1 = Ww1@TD1n ; z1 = Vw1@h1n ----
    {
      float absum = 0.f;
      if (tid < 512) {
        int j = tid * 2;
        float2 gi = cload2(&d_g1[j]),        gf = cload2(&d_g1[j + HD]);
        float2 gg = cload2(&d_g1[j + 2*HD]), go = cload2(&d_g1[j + 3*HD]);
        float2 cp = cload2(&d_c1[cur][j]);
        float2 rc = cload2(&d_rec2[cur][j]);
        float cA = sigf(gf.x) * cp.x + sigf(gi.x) * tanhfast(gg.x);
        float cB = sigf(gf.y) * cp.y + sigf(gi.y) * tanhfast(gg.y);
        float hA = sigf(go.x) * tanhfast(cA);
        float hB = sigf(go.y) * tanhfast(cB);
        float tA = hA - rc.x, tB = hB - rc.y;
        s_x0[j] = hA; s_x0[j + 1] = hB;
        s_x1[j] = tA; s_x1[j + 1] = tB;
        if (iswg0) {
          cstore2(&d_h1[nxt][j], hA, hB); cstore2(&d_c1[nxt][j], cA, cB);
          cstore2(&d_TD1[nxt][j], tA, tB);
        }
        absum = fabsf(tA) + fabsf(tB);
      }
      if (iswg0) {
        float tot = bredsum(absum, s_red);
        if (tid == 0) loss_acc += LAMF * tot;
      }
      __syncthreads();
      if (wid < HD) {
        float s = dot_pf<4>(pfB, s_x1, lane);
        s = wredsum(s);
        if (lane == 0) cstore(&d_BU1[wid], s + pfbias);
      } else if (wid < HD + CD) {
        float s = dot_pf<4>(pfB, s_x0, lane);
        s = wredsum(s);
        if (lane == 0) cstore(&d_z1[wid - HD], s + pfbias);
      }
      // prefetch S3 rows
      pf_row<8>(Wih2 + (size_t)wid * (2 * HD), lane, pfA);
      pf_row<4>(Whh2 + (size_t)wid * HD, lane, pfB);
      pfbias = bih2[wid] + bhh2[wid];
    }
    gbar(ep);

    // ---- S3: loss0 + softmax(z1) + predictions ; g2 matvec ----
    {
      if (tid < 512) {
        int j = tid * 2;
        float2 a = cload2(&d_BU1[j]);      *(float2*)(s_x0 + j) = a;
        float2 b = cload2(&d_TD2[cur][j]); *(float2*)(s_x1 + j) = b;
        float2 c = cload2(&d_h2[cur][j]);  *(float2*)(s_x2 + j) = c;
      }
      if (iswg0) {
        float u = 0.f;
        if (tid < CD) {
          float p  = cload(&d_rec1[cur][tid]);        // OLD rec1 (for step t)
          float xv = x[(size_t)t * CD + tid];
          u = xv * logf(p) + (1.f - xv) * logf(1.f - p);
        }
        float tot = bredsum(u, s_red);
        if (tid == 0) { loss_acc += -tot; fll_acc += -tot; }
        float z = (tid < CD) ? cload(&d_z1[tid]) : -INFINITY;
        float m = bredmax(z, s_red);
        float e = (tid < CD) ? __expf(z - m) : 0.f;
        float ssum = bredsum(e, s_red);
        if (tid < CD) {
          float p = e / ssum;
          cstore(&d_rec1[nxt][tid], p);               // rec1 for step t+1
          out[2 + (size_t)t * CD + tid] = p;          // predictions[t]
        }
      }
      __syncthreads();
      {
        float s = dot_pf<4>(pfA, s_x0, lane) + dot_pf<4>(pfA + 4, s_x1, lane)
                + dot_pf<4>(pfB, s_x2, lane);
        s = wredsum(s);
        if (lane == 0) cstore(&d_g2[wid], s + pfbias);
      }
      // prefetch S4 rows
      if (wid < HD)           { pf_row<4>(Ww2 + (size_t)wid * HD, lane, pfB); pfbias = Wb2[wid]; }
      else if (wid < 2 * HD)  { pf_row<4>(Vw2 + (size_t)(wid - HD) * HD, lane, pfB); pfbias = Vb2[wid - HD]; }
    }
    gbar(ep);

    // ---- S4: lstm2 cell ; BU2 = Ww2@TD2n ; rec2n = Vw2@h2n ----
    {
      float absum = 0.f;
      if (tid < 512) {
        int j = tid * 2;
        float2 gi = cload2(&d_g2[j]),        gf = cload2(&d_g2[j + HD]);
        float2 gg = cload2(&d_g2[j + 2*HD]), go = cload2(&d_g2[j + 3*HD]);
        float2 cp = cload2(&d_c2[cur][j]);
        float2 rc = cload2(&d_rec3[cur][j]);
        float cA = sigf(gf.x) * cp.x + sigf(gi.x) * tanhfast(gg.x);
        float cB = sigf(gf.y) * cp.y + sigf(gi.y) * tanhfast(gg.y);
        float hA = sigf(go.x) * tanhfast(cA);
        float hB = sigf(go.y) * tanhfast(cB);
        float tA = hA - rc.x, tB = hB - rc.y;
        s_x0[j] = hA; s_x0[j + 1] = hB;
        s_x1[j] = tA; s_x1[j + 1] = tB;
        if (iswg0) {
          cstore2(&d_h2[nxt][j], hA, hB); cstore2(&d_c2[nxt][j], cA, cB);
          cstore2(&d_TD2[nxt][j], tA, tB);
        }
        absum = fabsf(tA) + fabsf(tB);
      }
      if (iswg0) {
        float tot = bredsum(absum, s_red);
        if (tid == 0) loss_acc += (LAMF * LAMF) * tot;
      }
      __syncthreads();
      if (wid < HD) {
        float s = dot_pf<4>(pfB, s_x1, lane);
        s = wredsum(s);
        if (lane == 0) cstore(&d_BU2[wid], s + pfbias);
      } else if (wid < 2 * HD) {
        float s = dot_pf<4>(pfB, s_x0, lane);
        s = wredsum(s);
        if (lane == 0) cstore(&d_rec2[nxt][wid - HD], s + pfbias);
      }
      // prefetch S5 rows (skip at final step — S5 is skipped there)
      if (t < TT - 1) {
        pf_row<4>(Wih3 + (size_t)wid * HD, lane, pfA);
        pf_row<4>(Whh3 + (size_t)wid * HD, lane, pfB);
        pfbias = bih3[wid] + bhh3[wid];
        if (wid < HD) { pf_row<1>(Ww0 + (size_t)wid * CD, lane, pfC); pfbias2 = Wb0[wid]; }
      }
    }
    gbar(ep);

    // ---- S5: g3 = Wih3@BU2 + Whh3@h3 ; BU0(t+1) = Ww0@(x[t+1]-rec1n) ----
    if (t < TT - 1) {
      if (tid < 512) {
        int j = tid * 2;
        float2 a = cload2(&d_BU2[j]);     *(float2*)(s_x0 + j) = a;
        float2 c = cload2(&d_h3[cur][j]); *(float2*)(s_x2 + j) = c;
      }
      if (tid < CD)
        s_small[tid] = x[(size_t)(t + 1) * CD + tid] - cload(&d_rec1[nxt][tid]);
      __syncthreads();
      {
        float s = dot_pf<4>(pfA, s_x0, lane) + dot_pf<4>(pfB, s_x2, lane);
        s = wredsum(s);
        if (lane == 0) cstore(&d_g3[wid], s + pfbias);
      }
      if (wid < HD) {
        float s = dot_pf<1>(pfC, s_small, lane);
        s = wredsum(s);
        if (lane == 0) cstore(&d_BU0[wid], s + pfbias2);
      }
      // prefetch next S1 rows
      pf_row<8>(Wih1 + (size_t)wid * (2 * HD), lane, pfA);
      pf_row<4>(Whh1 + (size_t)wid * HD, lane, pfB);
      pfbias = bih1[wid] + bhh1[wid];
      if (wid < HD) { pf_row<4>(Vw3 + (size_t)wid * HD, lane, pfC); pfbias2 = Vb3[wid]; }
      gbar(ep);
    }
  }

  if (iswg0 && tid == 0) { out[0] = loss_acc; out[1] = fll_acc; }
}

extern "C" void kernel_launch(void* const* d_in, const int* in_sizes, int n_in,
                              void* d_out, int out_size, void* d_ws, size_t ws_size,
                              hipStream_t stream) {
  const float* x    = (const float*)d_in[0];
  const float* Wih1 = (const float*)d_in[1];
  const float* Whh1 = (const float*)d_in[2];
  const float* bih1 = (const float*)d_in[3];
  const float* bhh1 = (const float*)d_in[4];
  const float* Vw1  = (const float*)d_in[5];
  const float* Vb1  = (const float*)d_in[6];
  const float* Wih2 = (const float*)d_in[7];
  const float* Whh2 = (const float*)d_in[8];
  const float* bih2 = (const float*)d_in[9];
  const float* bhh2 = (const float*)d_in[10];
  const float* Vw2  = (const float*)d_in[11];
  const float* Vb2  = (const float*)d_in[12];
  const float* Wih3 = (const float*)d_in[13];
  const float* Whh3 = (const float*)d_in[14];
  const float* bih3 = (const float*)d_in[15];
  const float* bhh3 = (const float*)d_in[16];
  const float* Vw3  = (const float*)d_in[17];
  const float* Vb3  = (const float*)d_in[18];
  const float* Ww0  = (const float*)d_in[19];
  const float* Wb0  = (const float*)d_in[20];
  const float* Ww1  = (const float*)d_in[21];
  const float* Wb1  = (const float*)d_in[22];
  const float* Ww2  = (const float*)d_in[23];
  const float* Wb2  = (const float*)d_in[24];
  const float* r1   = (const float*)d_in[25];
  const float* r2   = (const float*)d_in[26];
  const float* r3   = (const float*)d_in[27];

  pc_init<<<1, NWG, 0, stream>>>();
  pc_main<<<NWG, NTH, 0, stream>>>(x, Wih1, Whh1, bih1, bhh1, Vw1, Vb1,
                                   Wih2, Whh2, bih2, bhh2, Vw2, Vb2,
                                   Wih3, Whh3, bih3, bhh3, Vw3, Vb3,
                                   Ww0, Wb0, Ww1, Wb1, Ww2, Wb2,
                                   r1, r2, r3, (float*)d_out);
}

// Round 5
// 35580.670 us; speedup vs baseline: 1.7485x; 1.7485x over previous
//
#include <hip/hip_runtime.h>
#include <math.h>

#define HD 1024
#define CD 256
#define TT 512
#define GD 4096                 // 4*H
#define NWG 256
#define NTH 1024
#define WPB (NTH/64)            // waves per block = 16
#define NWAVE (NWG*WPB)         // 4096
#define LAMF 0.05f

typedef unsigned long long ull;

// ---------------- persistent device scratch (re-initialized every call) ----
__device__ __align__(16) float d_g1[GD], d_g2[GD], d_g3[GD];
__device__ __align__(16) float d_BU0[HD], d_BU1[HD], d_BU2[HD];
__device__ __align__(16) float d_z1[CD];
__device__ __align__(16) float d_h1[2][HD], d_c1[2][HD], d_h2[2][HD], d_c2[2][HD], d_h3[2][HD], d_c3[2][HD];
__device__ __align__(16) float d_rec1[2][CD], d_rec2[2][HD], d_rec3[2][HD];
__device__ __align__(16) float d_TD1[2][HD], d_TD2[2][HD];
// distributed barrier state: one padded flag line per WG + one release line
__device__ int d_arr[NWG][32];
__device__ int d_rel;

__global__ void pc_init() { d_arr[threadIdx.x][0] = 0; if (threadIdx.x == 0) d_rel = 0; }

__device__ __forceinline__ float sigf(float x)     { return 1.f / (1.f + __expf(-x)); }
__device__ __forceinline__ float tanhfast(float x) { return 1.f - 2.f / (1.f + __expf(2.f * x)); }

// Coherent (cache-bypassing) accesses for cross-WG activation data. No
// cache-invalidating fences anywhere -> read-only weights stay hot in L1/L2.
__device__ __forceinline__ float cload(const float* p) {
  return __hip_atomic_load(p, __ATOMIC_RELAXED, __HIP_MEMORY_SCOPE_AGENT);
}
__device__ __forceinline__ void cstore(float* p, float v) {
  __hip_atomic_store(p, v, __ATOMIC_RELAXED, __HIP_MEMORY_SCOPE_AGENT);
}
__device__ __forceinline__ float2 cload2(const float* p) {
  union { ull u; float2 f; } c;
  c.u = __hip_atomic_load((const ull*)p, __ATOMIC_RELAXED, __HIP_MEMORY_SCOPE_AGENT);
  return c.f;
}
__device__ __forceinline__ void cstore2(float* p, float a, float b) {
  union { ull u; float2 f; } c;
  c.f = make_float2(a, b);
  __hip_atomic_store((ull*)p, c.u, __ATOMIC_RELAXED, __HIP_MEMORY_SCOPE_AGENT);
}

// Distributed epoch barrier (R3-proven). Arrival: each WG release-stores its
// epoch to its OWN cache line. WG0 lanes 1..255 each poll one flag; then WG0
// release-stores d_rel; other WGs poll d_rel. No cache-invalidating fences.
__device__ __forceinline__ void gbar(int& ep) {
  ++ep;
  __syncthreads();
  const int tid = threadIdx.x;
  if (blockIdx.x == 0) {
    if (tid >= 1 && tid < NWG) {
      while (__hip_atomic_load(&d_arr[tid][0], __ATOMIC_RELAXED, __HIP_MEMORY_SCOPE_AGENT) < ep)
        __builtin_amdgcn_s_sleep(1);
    }
    __syncthreads();
    if (tid == 0)
      __hip_atomic_store(&d_rel, ep, __ATOMIC_RELEASE, __HIP_MEMORY_SCOPE_AGENT);
  } else {
    if (tid == 0) {
      __hip_atomic_store(&d_arr[blockIdx.x][0], ep, __ATOMIC_RELEASE, __HIP_MEMORY_SCOPE_AGENT);
      while (__hip_atomic_load(&d_rel, __ATOMIC_RELAXED, __HIP_MEMORY_SCOPE_AGENT) < ep)
        __builtin_amdgcn_s_sleep(1);
    }
    __syncthreads();
  }
}

__device__ __forceinline__ float wredsum(float v) {
  #pragma unroll
  for (int off = 32; off; off >>= 1) v += __shfl_xor(v, off);
  return v;
}
__device__ __forceinline__ float wredmax(float v) {
  #pragma unroll
  for (int off = 32; off; off >>= 1) v = fmaxf(v, __shfl_xor(v, off));
  return v;
}

// block-wide reductions (P-stage only)
__device__ __forceinline__ float bredsum(float v, float* sred) {
  __syncthreads();
  v = wredsum(v);
  if ((threadIdx.x & 63) == 0) sred[threadIdx.x >> 6] = v;
  __syncthreads();
  float r = (threadIdx.x < WPB) ? sred[threadIdx.x] : 0.f;
  r += __shfl_xor(r, 1); r += __shfl_xor(r, 2); r += __shfl_xor(r, 4); r += __shfl_xor(r, 8);
  if (threadIdx.x == 0) sred[0] = r;
  __syncthreads();
  return sred[0];
}
__device__ __forceinline__ float bredmax(float v, float* sred) {
  __syncthreads();
  v = wredmax(v);
  if ((threadIdx.x & 63) == 0) sred[threadIdx.x >> 6] = v;
  __syncthreads();
  float r = (threadIdx.x < WPB) ? sred[threadIdx.x] : -INFINITY;
  r = fmaxf(r, __shfl_xor(r, 1)); r = fmaxf(r, __shfl_xor(r, 2));
  r = fmaxf(r, __shfl_xor(r, 4)); r = fmaxf(r, __shfl_xor(r, 8));
  if (threadIdx.x == 0) sred[0] = r;
  __syncthreads();
  return sred[0];
}

// prefetch NF4 float4 chunks of one weight row into registers
template<int NF4>
__device__ __forceinline__ void pf_row(const float* __restrict__ w, int lane, float4* pf) {
  #pragma unroll
  for (int i = 0; i < NF4; ++i) pf[i] = *(const float4*)(w + lane * 4 + i * 256);
}
// dot prefetched row chunks against an LDS vector
template<int NF4>
__device__ __forceinline__ float dot_pf(const float4* pf, const float* xv, int lane) {
  float a0 = 0.f, a1 = 0.f, a2 = 0.f, a3 = 0.f;
  #pragma unroll
  for (int i = 0; i < NF4; ++i) {
    const float4 vv = *(const float4*)(xv + lane * 4 + i * 256);
    a0 = fmaf(pf[i].x, vv.x, a0); a1 = fmaf(pf[i].y, vv.y, a1);
    a2 = fmaf(pf[i].z, vv.z, a2); a3 = fmaf(pf[i].w, vv.w, a3);
  }
  return (a0 + a1) + (a2 + a3);
}

__global__ __launch_bounds__(NTH, 1) void pc_main(
    const float* __restrict__ x,
    const float* __restrict__ Wih1, const float* __restrict__ Whh1,
    const float* __restrict__ bih1, const float* __restrict__ bhh1,
    const float* __restrict__ Vw1,  const float* __restrict__ Vb1,
    const float* __restrict__ Wih2, const float* __restrict__ Whh2,
    const float* __restrict__ bih2, const float* __restrict__ bhh2,
    const float* __restrict__ Vw2,  const float* __restrict__ Vb2,
    const float* __restrict__ Wih3, const float* __restrict__ Whh3,
    const float* __restrict__ bih3, const float* __restrict__ bhh3,
    const float* __restrict__ Vw3,  const float* __restrict__ Vb3,
    const float* __restrict__ Ww0,  const float* __restrict__ Wb0,
    const float* __restrict__ Ww1,  const float* __restrict__ Wb1,
    const float* __restrict__ Ww2,  const float* __restrict__ Wb2,
    const float* __restrict__ r1,   const float* __restrict__ r2,
    const float* __restrict__ r3,
    float* __restrict__ out) {
  const int tid  = threadIdx.x;
  const int lane = tid & 63;
  const int wid  = blockIdx.x * WPB + (tid >> 6);
  const int sjob = NWAVE - 1 - wid;     // secondary-job id (top WGs get them)
  const bool iswg0 = (blockIdx.x == 0);
  const bool w0    = iswg0 && tid < 64; // the "scalar" wave

  __shared__ __align__(16) float s_x0[HD];
  __shared__ __align__(16) float s_x1[HD];
  __shared__ __align__(16) float s_x2[HD];
  __shared__ __align__(16) float s_aux[HD];
  __shared__ __align__(16) float s_small[CD];
  __shared__ float s_red[WPB];

  float4 pfA[8], pfB[4], pfC[4];
  float  pfbias = 0.f, pfbias2 = 0.f;
  float  p_reg[4];                      // wave0/WG0: current rec1 (4 per lane)
  int ep = 0;
  float loss_acc = 0.f, fll_acc = 0.f;

  // ---------------- Stage P: init state + BU0(0) + prefetch S1(0) ----------
  {
    float z = (tid < CD) ? r1[tid] : -INFINITY;
    float m = bredmax(z, s_red);
    float e = (tid < CD) ? __expf(z - m) : 0.f;
    float ssum = bredsum(e, s_red);
    if (tid < CD) {
      float p = e / ssum;               // rec1(0) = softmax(r1)
      s_small[tid] = x[tid] - p;        // TD0 at t=0
      s_aux[tid] = p;
    }
    if (iswg0) {
      for (int j = tid; j < HD; j += NTH) {
        cstore(&d_h1[0][j], 0.f); cstore(&d_c1[0][j], 0.f);
        cstore(&d_h2[0][j], 0.f); cstore(&d_c2[0][j], 0.f);
        cstore(&d_h3[0][j], 0.f); cstore(&d_c3[0][j], 0.f);
        cstore(&d_TD1[0][j], 0.f); cstore(&d_TD2[0][j], 0.f);
        cstore(&d_rec2[0][j], r2[j]); cstore(&d_rec3[0][j], r3[j]);
      }
    }
    __syncthreads();
    if (w0) {
      #pragma unroll
      for (int i = 0; i < 4; ++i) p_reg[i] = s_aux[tid * 4 + i];
    }
    if (sjob < HD) {                    // BU0(0), direct (one-time)
      const float4 w4 = *(const float4*)(Ww0 + (size_t)sjob * CD + lane * 4);
      const float4 xv = *(const float4*)(s_small + lane * 4);
      float s = fmaf(w4.x, xv.x, fmaf(w4.y, xv.y, fmaf(w4.z, xv.z, w4.w * xv.w)));
      s = wredsum(s);
      if (lane == 0) cstore(&d_BU0[sjob], s + Wb0[sjob]);
    }
    pf_row<8>(Wih1 + (size_t)wid * (2 * HD), lane, pfA);
    pf_row<4>(Whh1 + (size_t)wid * HD, lane, pfB);
    pfbias = bih1[wid] + bhh1[wid];
  }
  gbar(ep);

  for (int t = 0; t < TT; ++t) {
    const int cur = t & 1, nxt = cur ^ 1;

    // ---- S1: g1 matvec ; cell3 + rec3 = Vw3@h3n (t>0) ----
    {
      if (tid < 512) {
        int j = tid * 2;
        float2 a = cload2(&d_BU0[j]);      *(float2*)(s_x0 + j) = a;
        float2 b = cload2(&d_TD1[cur][j]); *(float2*)(s_x1 + j) = b;
        float2 c = cload2(&d_h1[cur][j]);  *(float2*)(s_x2 + j) = c;
      }
      if (t > 0 && tid < 512) {
        int j = tid * 2;
        float2 gi = cload2(&d_g3[j]),        gf = cload2(&d_g3[j + HD]);
        float2 gg = cload2(&d_g3[j + 2*HD]), go = cload2(&d_g3[j + 3*HD]);
        float2 cp = cload2(&d_c3[nxt][j]);   // (t-1)&1 == nxt
        float cA = sigf(gf.x) * cp.x + sigf(gi.x) * tanhfast(gg.x);
        float cB = sigf(gf.y) * cp.y + sigf(gi.y) * tanhfast(gg.y);
        float hA = sigf(go.x) * tanhfast(cA);
        float hB = sigf(go.y) * tanhfast(cB);
        s_aux[j] = hA; s_aux[j + 1] = hB;
        if (iswg0) { cstore2(&d_h3[cur][j], hA, hB); cstore2(&d_c3[cur][j], cA, cB); }
      }
      __syncthreads();
      {
        float s = dot_pf<4>(pfA, s_x0, lane) + dot_pf<4>(pfA + 4, s_x1, lane)
                + dot_pf<4>(pfB, s_x2, lane);
        s = wredsum(s);
        if (lane == 0) cstore(&d_g1[wid], s + pfbias);
      }
      if (t > 0 && sjob < HD) {
        float s = dot_pf<4>(pfC, s_aux, lane);
        s = wredsum(s);
        if (lane == 0) cstore(&d_rec3[cur][sjob], s + pfbias2);
      }
      // prefetch S3's big rows + S2's secondary rows
      pf_row<8>(Wih2 + (size_t)wid * (2 * HD), lane, pfA);
      pf_row<4>(Whh2 + (size_t)wid * HD, lane, pfB);
      pfbias = bih2[wid] + bhh2[wid];
      if (sjob < HD)           { pf_row<4>(Ww1 + (size_t)sjob * HD, lane, pfC); pfbias2 = Wb1[sjob]; }
      else if (sjob < HD + CD) { pf_row<4>(Vw1 + (size_t)(sjob - HD) * HD, lane, pfC); pfbias2 = Vb1[sjob - HD]; }
    }
    gbar(ep);

    // ---- S2: cell1 ; BU1 = Ww1@TD1n ; z1 = Vw1@h1n ----
    {
      if (tid < 512) {
        int j = tid * 2;
        float2 gi = cload2(&d_g1[j]),        gf = cload2(&d_g1[j + HD]);
        float2 gg = cload2(&d_g1[j + 2*HD]), go = cload2(&d_g1[j + 3*HD]);
        float2 cp = cload2(&d_c1[cur][j]);
        float2 rc = cload2(&d_rec2[cur][j]);
        float cA = sigf(gf.x) * cp.x + sigf(gi.x) * tanhfast(gg.x);
        float cB = sigf(gf.y) * cp.y + sigf(gi.y) * tanhfast(gg.y);
        float hA = sigf(go.x) * tanhfast(cA);
        float hB = sigf(go.y) * tanhfast(cB);
        float tA = hA - rc.x, tB = hB - rc.y;
        s_x0[j] = hA; s_x0[j + 1] = hB;
        s_x1[j] = tA; s_x1[j + 1] = tB;
        if (iswg0) {
          cstore2(&d_h1[nxt][j], hA, hB); cstore2(&d_c1[nxt][j], cA, cB);
          cstore2(&d_TD1[nxt][j], tA, tB);
        }
      }
      __syncthreads();
      if (w0) {                         // |TD1| sum, single wave
        float a = 0.f;
        #pragma unroll
        for (int k = 0; k < 16; ++k) a += fabsf(s_x1[tid + 64 * k]);
        a = wredsum(a);
        if (tid == 0) loss_acc += LAMF * a;
      }
      if (sjob < HD) {
        float s = dot_pf<4>(pfC, s_x1, lane);
        s = wredsum(s);
        if (lane == 0) cstore(&d_BU1[sjob], s + pfbias2);
      } else if (sjob < HD + CD) {
        float s = dot_pf<4>(pfC, s_x0, lane);
        s = wredsum(s);
        if (lane == 0) cstore(&d_z1[sjob - HD], s + pfbias2);
      }
      // prefetch S4's secondary rows
      if (sjob < HD)          { pf_row<4>(Ww2 + (size_t)sjob * HD, lane, pfC); pfbias2 = Wb2[sjob]; }
      else if (sjob < 2 * HD) { pf_row<4>(Vw2 + (size_t)(sjob - HD) * HD, lane, pfC); pfbias2 = Vb2[sjob - HD]; }
    }
    gbar(ep);

    // ---- S3: loss0 + softmax(z1) + predictions (wave0) ; g2 matvec ----
    {
      if (tid < 512) {
        int j = tid * 2;
        float2 a = cload2(&d_BU1[j]);      *(float2*)(s_x0 + j) = a;
        float2 b = cload2(&d_TD2[cur][j]); *(float2*)(s_x1 + j) = b;
        float2 c = cload2(&d_h2[cur][j]);  *(float2*)(s_x2 + j) = c;
      }
      if (w0) {
        const float4 xv = *(const float4*)(x + (size_t)t * CD + tid * 4);
        float u = xv.x * __logf(p_reg[0]) + (1.f - xv.x) * __logf(1.f - p_reg[0])
                + xv.y * __logf(p_reg[1]) + (1.f - xv.y) * __logf(1.f - p_reg[1])
                + xv.z * __logf(p_reg[2]) + (1.f - xv.z) * __logf(1.f - p_reg[2])
                + xv.w * __logf(p_reg[3]) + (1.f - xv.w) * __logf(1.f - p_reg[3]);
        float ut = wredsum(u);
        float z0 = cload(&d_z1[tid * 4 + 0]), z1v = cload(&d_z1[tid * 4 + 1]);
        float z2 = cload(&d_z1[tid * 4 + 2]), z3v = cload(&d_z1[tid * 4 + 3]);
        float m = wredmax(fmaxf(fmaxf(z0, z1v), fmaxf(z2, z3v)));
        float e0 = __expf(z0 - m), e1 = __expf(z1v - m);
        float e2 = __expf(z2 - m), e3 = __expf(z3v - m);
        float inv = 1.f / wredsum((e0 + e1) + (e2 + e3));
        p_reg[0] = e0 * inv; p_reg[1] = e1 * inv;
        p_reg[2] = e2 * inv; p_reg[3] = e3 * inv;
        cstore2(&d_rec1[nxt][tid * 4], p_reg[0], p_reg[1]);
        cstore2(&d_rec1[nxt][tid * 4 + 2], p_reg[2], p_reg[3]);
        float* po = out + 2 + (size_t)t * CD + tid * 4;
        *(float2*)po = make_float2(p_reg[0], p_reg[1]);
        *(float2*)(po + 2) = make_float2(p_reg[2], p_reg[3]);
        if (tid == 0) { loss_acc -= ut; fll_acc -= ut; }
      }
      __syncthreads();
      {
        float s = dot_pf<4>(pfA, s_x0, lane) + dot_pf<4>(pfA + 4, s_x1, lane)
                + dot_pf<4>(pfB, s_x2, lane);
        s = wredsum(s);
        if (lane == 0) cstore(&d_g2[wid], s + pfbias);
      }
      // prefetch S5's big rows
      pf_row<4>(Wih3 + (size_t)wid * HD, lane, pfA);
      pf_row<4>(Whh3 + (size_t)wid * HD, lane, pfB);
      pfbias = bih3[wid] + bhh3[wid];
    }
    gbar(ep);

    // ---- S4: cell2 ; BU2 = Ww2@TD2n ; rec2n = Vw2@h2n ----
    {
      if (tid < 512) {
        int j = tid * 2;
        float2 gi = cload2(&d_g2[j]),        gf = cload2(&d_g2[j + HD]);
        float2 gg = cload2(&d_g2[j + 2*HD]), go = cload2(&d_g2[j + 3*HD]);
        float2 cp = cload2(&d_c2[cur][j]);
        float2 rc = cload2(&d_rec3[cur][j]);
        float cA = sigf(gf.x) * cp.x + sigf(gi.x) * tanhfast(gg.x);
        float cB = sigf(gf.y) * cp.y + sigf(gi.y) * tanhfast(gg.y);
        float hA = sigf(go.x) * tanhfast(cA);
        float hB = sigf(go.y) * tanhfast(cB);
        float tA = hA - rc.x, tB = hB - rc.y;
        s_x0[j] = hA; s_x0[j + 1] = hB;
        s_x1[j] = tA; s_x1[j + 1] = tB;
        if (iswg0) {
          cstore2(&d_h2[nxt][j], hA, hB); cstore2(&d_c2[nxt][j], cA, cB);
          cstore2(&d_TD2[nxt][j], tA, tB);
        }
      }
      __syncthreads();
      if (w0) {                         // |TD2| sum, single wave
        float a = 0.f;
        #pragma unroll
        for (int k = 0; k < 16; ++k) a += fabsf(s_x1[tid + 64 * k]);
        a = wredsum(a);
        if (tid == 0) loss_acc += (LAMF * LAMF) * a;
      }
      if (sjob < HD) {
        float s = dot_pf<4>(pfC, s_x1, lane);
        s = wredsum(s);
        if (lane == 0) cstore(&d_BU2[sjob], s + pfbias2);
      } else if (sjob < 2 * HD) {
        float s = dot_pf<4>(pfC, s_x0, lane);
        s = wredsum(s);
        if (lane == 0) cstore(&d_rec2[nxt][sjob - HD], s + pfbias2);
      }
      if (t < TT - 1 && sjob < HD) {    // prefetch S5's Ww0 row
        pf_row<1>(Ww0 + (size_t)sjob * CD, lane, pfC);
        pfbias2 = Wb0[sjob];
      }
    }
    gbar(ep);

    // ---- S5: g3 = Wih3@BU2 + Whh3@h3 ; BU0' = Ww0@(x[t+1]-rec1n) ----
    if (t < TT - 1) {
      if (tid < 512) {
        int j = tid * 2;
        float2 a = cload2(&d_BU2[j]);     *(float2*)(s_x0 + j) = a;
        float2 c = cload2(&d_h3[cur][j]); *(float2*)(s_x2 + j) = c;
      }
      if (tid < CD)
        s_small[tid] = x[(size_t)(t + 1) * CD + tid] - cload(&d_rec1[nxt][tid]);
      __syncthreads();
      {
        float s = dot_pf<4>(pfA, s_x0, lane) + dot_pf<4>(pfB, s_x2, lane);
        s = wredsum(s);
        if (lane == 0) cstore(&d_g3[wid], s + pfbias);
      }
      if (sjob < HD) {
        float s = dot_pf<1>(pfC, s_small, lane);
        s = wredsum(s);
        if (lane == 0) cstore(&d_BU0[sjob], s + pfbias2);
      }
      // prefetch next S1's rows
      pf_row<8>(Wih1 + (size_t)wid * (2 * HD), lane, pfA);
      pf_row<4>(Whh1 + (size_t)wid * HD, lane, pfB);
      pfbias = bih1[wid] + bhh1[wid];
      if (sjob < HD) { pf_row<4>(Vw3 + (size_t)sjob * HD, lane, pfC); pfbias2 = Vb3[sjob]; }
      gbar(ep);
    }
  }

  if (iswg0 && tid == 0) { out[0] = loss_acc; out[1] = fll_acc; }
}

extern "C" void kernel_launch(void* const* d_in, const int* in_sizes, int n_in,
                              void* d_out, int out_size, void* d_ws, size_t ws_size,
                              hipStream_t stream) {
  const float* x    = (const float*)d_in[0];
  const float* Wih1 = (const float*)d_in[1];
  const float* Whh1 = (const float*)d_in[2];
  const float* bih1 = (const float*)d_in[3];
  const float* bhh1 = (const float*)d_in[4];
  const float* Vw1  = (const float*)d_in[5];
  const float* Vb1  = (const float*)d_in[6];
  const float* Wih2 = (const float*)d_in[7];
  const float* Whh2 = (const float*)d_in[8];
  const float* bih2 = (const float*)d_in[9];
  const float* bhh2 = (const float*)d_in[10];
  const float* Vw2  = (const float*)d_in[11];
  const float* Vb2  = (const float*)d_in[12];
  const float* Wih3 = (const float*)d_in[13];
  const float* Whh3 = (const float*)d_in[14];
  const float* bih3 = (const float*)d_in[15];
  const float* bhh3 = (const float*)d_in[16];
  const float* Vw3  = (const float*)d_in[17];
  const float* Vb3  = (const float*)d_in[18];
  const float* Ww0  = (const float*)d_in[19];
  const float* Wb0  = (const float*)d_in[20];
  const float* Ww1  = (const float*)d_in[21];
  const float* Wb1  = (const float*)d_in[22];
  const float* Ww2  = (const float*)d_in[23];
  const float* Wb2  = (const float*)d_in[24];
  const float* r1   = (const float*)d_in[25];
  const float* r2   = (const float*)d_in[26];
  const float* r3   = (const float*)d_in[27];

  pc_init<<<1, NWG, 0, stream>>>();
  pc_main<<<NWG, NTH, 0, stream>>>(x, Wih1, Whh1, bih1, bhh1, Vw1, Vb1,
                                   Wih2, Whh2, bih2, bhh2, Vw2, Vb2,
                                   Wih3, Whh3, bih3, bhh3, Vw3, Vb3,
                                   Ww0, Wb0, Ww1, Wb1, Ww2, Wb2,
                                   r1, r2, r3, (float*)d_out);
}

// Round 6
// 23536.076 us; speedup vs baseline: 2.6433x; 1.5118x over previous
//
#include <hip/hip_runtime.h>
#include <math.h>

#define HD 1024
#define CD 256
#define TT 512
#define GD 4096                 // 4*H
#define NWG 256
#define NTH 1024
#define WPB (NTH/64)            // 16 waves per block
#define NWAVE (NWG*WPB)         // 4096
#define LAMF 0.05f

typedef unsigned long long ull;

// ---------------- folded matrices (computed by pc_fold every call) --------
__device__ __align__(16) float d_M1[GD * CD];   //  4 MB : Wih1[:,:H] @ Ww0
__device__ __align__(16) float d_M2[GD * HD];   // 16 MB : Wih2[:,:H] @ Ww1
__device__ __align__(16) float d_M3[GD * HD];   // 16 MB : Wih3      @ Ww2

// ---------------- persistent state (re-initialized every call) ------------
__device__ __align__(16) float d_g1[GD], d_g2[GD], d_g3[GD];
__device__ __align__(16) float d_z1[CD];
__device__ __align__(16) float d_h1[2][HD], d_c1[2][HD], d_h2[2][HD], d_c2[2][HD], d_h3[2][HD], d_c3[2][HD];
__device__ __align__(16) float d_rec2[2][HD], d_rec3[2][HD];
__device__ __align__(16) float d_TD1[2][HD], d_TD2[2][HD];
__device__ int d_arr[NWG][32];
__device__ int d_rel;

__global__ void pc_init() { d_arr[threadIdx.x][0] = 0; if (threadIdx.x == 0) d_rel = 0; }

__device__ __forceinline__ float sigf(float x)     { return 1.f / (1.f + __expf(-x)); }
__device__ __forceinline__ float tanhfast(float x) { return 1.f - 2.f / (1.f + __expf(2.f * x)); }

// Coherent (cache-bypassing) accesses for cross-WG activation data; weights
// stay in normal cached path (no invalidating fences anywhere).
__device__ __forceinline__ float cload(const float* p) {
  return __hip_atomic_load(p, __ATOMIC_RELAXED, __HIP_MEMORY_SCOPE_AGENT);
}
__device__ __forceinline__ void cstore(float* p, float v) {
  __hip_atomic_store(p, v, __ATOMIC_RELAXED, __HIP_MEMORY_SCOPE_AGENT);
}
__device__ __forceinline__ float2 cload2(const float* p) {
  union { ull u; float2 f; } c;
  c.u = __hip_atomic_load((const ull*)p, __ATOMIC_RELAXED, __HIP_MEMORY_SCOPE_AGENT);
  return c.f;
}
__device__ __forceinline__ void cstore2(float* p, float a, float b) {
  union { ull u; float2 f; } c;
  c.f = make_float2(a, b);
  __hip_atomic_store((ull*)p, c.u, __ATOMIC_RELAXED, __HIP_MEMORY_SCOPE_AGENT);
}

// Distributed epoch barrier (R3-proven).
__device__ __forceinline__ void gbar(int& ep) {
  ++ep;
  __syncthreads();
  const int tid = threadIdx.x;
  if (blockIdx.x == 0) {
    if (tid >= 1 && tid < NWG) {
      while (__hip_atomic_load(&d_arr[tid][0], __ATOMIC_RELAXED, __HIP_MEMORY_SCOPE_AGENT) < ep)
        __builtin_amdgcn_s_sleep(1);
    }
    __syncthreads();
    if (tid == 0)
      __hip_atomic_store(&d_rel, ep, __ATOMIC_RELEASE, __HIP_MEMORY_SCOPE_AGENT);
  } else {
    if (tid == 0) {
      __hip_atomic_store(&d_arr[blockIdx.x][0], ep, __ATOMIC_RELEASE, __HIP_MEMORY_SCOPE_AGENT);
      while (__hip_atomic_load(&d_rel, __ATOMIC_RELAXED, __HIP_MEMORY_SCOPE_AGENT) < ep)
        __builtin_amdgcn_s_sleep(1);
    }
    __syncthreads();
  }
}

__device__ __forceinline__ float wredsum(float v) {
  #pragma unroll
  for (int off = 32; off; off >>= 1) v += __shfl_xor(v, off);
  return v;
}
__device__ __forceinline__ float wredmax(float v) {
  #pragma unroll
  for (int off = 32; off; off >>= 1) v = fmaxf(v, __shfl_xor(v, off));
  return v;
}

// per-lane partial dot of one weight row against an LDS vector (n % 256 == 0)
__device__ __forceinline__ float dotp(const float* __restrict__ w, const float* xv, int n, int lane) {
  float a0 = 0.f, a1 = 0.f, a2 = 0.f, a3 = 0.f;
  for (int c = lane * 4; c < n; c += 256) {
    const float4 wv = *(const float4*)(w + c);
    const float4 vv = *(const float4*)(xv + c);
    a0 = fmaf(wv.x, vv.x, a0);
    a1 = fmaf(wv.y, vv.y, a1);
    a2 = fmaf(wv.z, vv.z, a2);
    a3 = fmaf(wv.w, vv.w, a3);
  }
  return (a0 + a1) + (a2 + a3);
}

// ---------------- fold GEMM: C[4096 x N] = A[4096 x 1024] @ B[1024 x N] ----
// 64x64 tiles, BK=16, 256 threads, 4x4 per thread.
__global__ __launch_bounds__(256) void pc_fold(
    const float* __restrict__ Wih1, const float* __restrict__ Wih2,
    const float* __restrict__ Wih3, const float* __restrict__ Ww0,
    const float* __restrict__ Ww1,  const float* __restrict__ Ww2) {
  int b = blockIdx.x;
  const float* A; const float* B; float* C; int N, lda;
  if (b < 256)        { A = Wih1; B = Ww0; C = d_M1; N = CD; lda = 2 * HD; }
  else if (b < 1280)  { A = Wih2; B = Ww1; C = d_M2; N = HD; lda = 2 * HD; b -= 256; }
  else                { A = Wih3; B = Ww2; C = d_M3; N = HD; lda = HD;     b -= 1280; }
  const int ctiles = N >> 6;
  const int rt = b / ctiles, ct = b - rt * ctiles;
  const int tid = threadIdx.x;
  const int tx = tid & 15, ty = tid >> 4;

  __shared__ float sA[16][65];   // [k][row], padded
  __shared__ float sB[16][64];   // [k][col]

  float acc[4][4] = {};
  const int ar = tid >> 2, aq = tid & 3;      // A-tile load mapping
  const int br = tid >> 4, bq = tid & 15;     // B-tile load mapping

  for (int kk = 0; kk < HD; kk += 16) {
    float4 av = *(const float4*)(A + (size_t)(rt * 64 + ar) * lda + kk + aq * 4);
    float4 bv = *(const float4*)(B + (size_t)(kk + br) * N + ct * 64 + bq * 4);
    __syncthreads();
    sA[aq * 4 + 0][ar] = av.x; sA[aq * 4 + 1][ar] = av.y;
    sA[aq * 4 + 2][ar] = av.z; sA[aq * 4 + 3][ar] = av.w;
    *(float4*)&sB[br][bq * 4] = bv;
    __syncthreads();
    #pragma unroll
    for (int k = 0; k < 16; ++k) {
      const float4 b4 = *(const float4*)&sB[k][tx * 4];
      const float a0 = sA[k][ty * 4 + 0], a1 = sA[k][ty * 4 + 1];
      const float a2 = sA[k][ty * 4 + 2], a3 = sA[k][ty * 4 + 3];
      acc[0][0] = fmaf(a0, b4.x, acc[0][0]); acc[0][1] = fmaf(a0, b4.y, acc[0][1]);
      acc[0][2] = fmaf(a0, b4.z, acc[0][2]); acc[0][3] = fmaf(a0, b4.w, acc[0][3]);
      acc[1][0] = fmaf(a1, b4.x, acc[1][0]); acc[1][1] = fmaf(a1, b4.y, acc[1][1]);
      acc[1][2] = fmaf(a1, b4.z, acc[1][2]); acc[1][3] = fmaf(a1, b4.w, acc[1][3]);
      acc[2][0] = fmaf(a2, b4.x, acc[2][0]); acc[2][1] = fmaf(a2, b4.y, acc[2][1]);
      acc[2][2] = fmaf(a2, b4.z, acc[2][2]); acc[2][3] = fmaf(a2, b4.w, acc[2][3]);
      acc[3][0] = fmaf(a3, b4.x, acc[3][0]); acc[3][1] = fmaf(a3, b4.y, acc[3][1]);
      acc[3][2] = fmaf(a3, b4.z, acc[3][2]); acc[3][3] = fmaf(a3, b4.w, acc[3][3]);
    }
  }
  #pragma unroll
  for (int i = 0; i < 4; ++i) {
    float4 r = make_float4(acc[i][0], acc[i][1], acc[i][2], acc[i][3]);
    *(float4*)(C + (size_t)(rt * 64 + ty * 4 + i) * N + ct * 64 + tx * 4) = r;
  }
}

__global__ __launch_bounds__(NTH, 1) void pc_main(
    const float* __restrict__ x,
    const float* __restrict__ Wih1, const float* __restrict__ Whh1,
    const float* __restrict__ bih1, const float* __restrict__ bhh1,
    const float* __restrict__ Vw1,  const float* __restrict__ Vb1,
    const float* __restrict__ Wih2, const float* __restrict__ Whh2,
    const float* __restrict__ bih2, const float* __restrict__ bhh2,
    const float* __restrict__ Vw2,  const float* __restrict__ Vb2,
    const float* __restrict__ Wih3, const float* __restrict__ Whh3,
    const float* __restrict__ bih3, const float* __restrict__ bhh3,
    const float* __restrict__ Vw3,  const float* __restrict__ Vb3,
    const float* __restrict__ Ww0,  const float* __restrict__ Wb0,
    const float* __restrict__ Ww1,  const float* __restrict__ Wb1,
    const float* __restrict__ Ww2,  const float* __restrict__ Wb2,
    const float* __restrict__ r1,   const float* __restrict__ r2,
    const float* __restrict__ r3,
    float* __restrict__ out) {
  const int tid  = threadIdx.x;
  const int lane = tid & 63;
  const int bid  = blockIdx.x;
  const int wid  = bid * WPB + (tid >> 6);
  const bool iswg0 = (bid == 0);
  const bool w0    = iswg0 && tid < 64;

  // secondary-job mapping: every 4th wave owns one HD-job; every 16th a CD-job
  const int jA = ((wid & 3) == 0)  ? (wid >> 2) : -1;   // rec3 (A) / rec2 (C)
  const int jB = ((wid & 15) == 0) ? (wid >> 4) : -1;   // z1 (B)

  __shared__ __align__(16) float s0[HD], s1[HD], s2[HD], s3[HD];
  __shared__ __align__(16) float s_small[CD];

  int ep = 0;
  float loss_acc = 0.f, fll_acc = 0.f;
  float b1, b2, b3, vbA = 0.f, vbB = 0.f, vbC = 0.f;

  // ---------------- Stage P: init state + fold biases -----------------------
  {
    if (tid < 512) {
      int j = tid * 2;
      *(float2*)(s0 + j) = *(const float2*)(Wb0 + j);
      *(float2*)(s1 + j) = *(const float2*)(Wb1 + j);
      *(float2*)(s2 + j) = *(const float2*)(Wb2 + j);
    }
    if (iswg0) {
      for (int j = tid; j < HD; j += NTH) {
        cstore(&d_h1[0][j], 0.f); cstore(&d_c1[0][j], 0.f);
        cstore(&d_h2[0][j], 0.f); cstore(&d_c2[0][j], 0.f);
        cstore(&d_h3[0][j], 0.f); cstore(&d_c3[0][j], 0.f);
        cstore(&d_TD1[0][j], 0.f); cstore(&d_TD2[0][j], 0.f);
        cstore(&d_rec2[0][j], r2[j]); cstore(&d_rec3[0][j], r3[j]);
      }
      if (tid < CD) cstore(&d_z1[tid], r1[tid]);
    }
    __syncthreads();
    b1 = bih1[wid] + bhh1[wid] + wredsum(dotp(Wih1 + (size_t)wid * 2 * HD, s0, HD, lane));
    b2 = bih2[wid] + bhh2[wid] + wredsum(dotp(Wih2 + (size_t)wid * 2 * HD, s1, HD, lane));
    b3 = bih3[wid] + bhh3[wid] + wredsum(dotp(Wih3 + (size_t)wid * HD, s2, HD, lane));
    if (jA >= 0) { vbA = Vb3[jA]; vbC = Vb2[jA]; }
    if (jB >= 0) { vbB = Vb1[jB]; }
  }
  gbar(ep);

  for (int t = 0; t < TT; ++t) {
    const int cur = t & 1, nxt = cur ^ 1;

    // ======== ROUND A: g1 = M1@TD0 + Wih1b@TD1 + Whh1@h1 ; cell3+rec3 ======
    {
      if (tid < 512) {
        int j = tid * 2;
        *(float2*)(s2 + j) = cload2(&d_TD1[cur][j]);
        *(float2*)(s3 + j) = cload2(&d_h1[cur][j]);
        if (t > 0) {
          float2 gi = cload2(&d_g3[j]),        gf = cload2(&d_g3[j + HD]);
          float2 gg = cload2(&d_g3[j + 2*HD]), go = cload2(&d_g3[j + 3*HD]);
          float2 cp = cload2(&d_c3[nxt][j]);   // c3 of step t-1
          float cA = sigf(gf.x) * cp.x + sigf(gi.x) * tanhfast(gg.x);
          float cB = sigf(gf.y) * cp.y + sigf(gi.y) * tanhfast(gg.y);
          float hA = sigf(go.x) * tanhfast(cA);
          float hB = sigf(go.y) * tanhfast(cB);
          s1[j] = hA; s1[j + 1] = hB;
          if ((tid >> 1) == bid) {             // spread state stores
            cstore2(&d_h3[cur][j], hA, hB); cstore2(&d_c3[cur][j], cA, cB);
          }
        }
      }
      if (tid < 64) {                          // redundant softmax(z1) per WG
        float2 za = cload2(&d_z1[tid * 4]), zb = cload2(&d_z1[tid * 4 + 2]);
        float m = wredmax(fmaxf(fmaxf(za.x, za.y), fmaxf(zb.x, zb.y)));
        float e0 = __expf(za.x - m), e1 = __expf(za.y - m);
        float e2 = __expf(zb.x - m), e3 = __expf(zb.y - m);
        float inv = 1.f / wredsum((e0 + e1) + (e2 + e3));
        float p0 = e0 * inv, p1 = e1 * inv, p2 = e2 * inv, p3 = e3 * inv;
        const float4 xv = *(const float4*)(x + (size_t)t * CD + tid * 4);
        s_small[tid * 4 + 0] = xv.x - p0; s_small[tid * 4 + 1] = xv.y - p1;
        s_small[tid * 4 + 2] = xv.z - p2; s_small[tid * 4 + 3] = xv.w - p3;
        if (iswg0) {
          float u = xv.x * __logf(p0) + (1.f - xv.x) * __logf(1.f - p0)
                  + xv.y * __logf(p1) + (1.f - xv.y) * __logf(1.f - p1)
                  + xv.z * __logf(p2) + (1.f - xv.z) * __logf(1.f - p2)
                  + xv.w * __logf(p3) + (1.f - xv.w) * __logf(1.f - p3);
          u = wredsum(u);
          if (t > 0) {
            float* po = out + 2 + (size_t)(t - 1) * CD + tid * 4;
            po[0] = p0; po[1] = p1; po[2] = p2; po[3] = p3;
          }
          if (tid == 0) { loss_acc -= u; fll_acc -= u; }
        }
      }
      __syncthreads();
      {
        float s = dotp(d_M1 + (size_t)wid * CD, s_small, CD, lane)
                + dotp(Wih1 + (size_t)wid * 2 * HD + HD, s2, HD, lane)
                + dotp(Whh1 + (size_t)wid * HD, s3, HD, lane);
        s = wredsum(s);
        if (lane == 0) cstore(&d_g1[wid], s + b1);
      }
      if (t > 0 && jA >= 0) {
        float s = wredsum(dotp(Vw3 + (size_t)jA * HD, s1, HD, lane));
        if (lane == 0) cstore(&d_rec3[cur][jA], s + vbA);
      }
    }
    gbar(ep);

    // ======== ROUND B: cell1 ; g2 = M2@TD1n + Wih2b@TD2 + Whh2@h2 ; z1 =====
    {
      if (tid < 512) {
        int j = tid * 2;
        float2 gi = cload2(&d_g1[j]),        gf = cload2(&d_g1[j + HD]);
        float2 gg = cload2(&d_g1[j + 2*HD]), go = cload2(&d_g1[j + 3*HD]);
        float2 cp = cload2(&d_c1[cur][j]);
        float2 rc = cload2(&d_rec2[cur][j]);
        float cA = sigf(gf.x) * cp.x + sigf(gi.x) * tanhfast(gg.x);
        float cB = sigf(gf.y) * cp.y + sigf(gi.y) * tanhfast(gg.y);
        float hA = sigf(go.x) * tanhfast(cA);
        float hB = sigf(go.y) * tanhfast(cB);
        float tA = hA - rc.x, tB = hB - rc.y;
        s0[j] = hA; s0[j + 1] = hB;
        s1[j] = tA; s1[j + 1] = tB;
        *(float2*)(s2 + j) = cload2(&d_TD2[cur][j]);
        *(float2*)(s3 + j) = cload2(&d_h2[cur][j]);
        if ((tid >> 1) == bid) {
          cstore2(&d_h1[nxt][j], hA, hB); cstore2(&d_c1[nxt][j], cA, cB);
          cstore2(&d_TD1[nxt][j], tA, tB);
        }
      }
      __syncthreads();
      if (w0) {
        float a = 0.f;
        #pragma unroll
        for (int k = 0; k < 16; ++k) a += fabsf(s1[tid + 64 * k]);
        a = wredsum(a);
        if (tid == 0) loss_acc += LAMF * a;
      }
      {
        float s = dotp(d_M2 + (size_t)wid * HD, s1, HD, lane)
                + dotp(Wih2 + (size_t)wid * 2 * HD + HD, s2, HD, lane)
                + dotp(Whh2 + (size_t)wid * HD, s3, HD, lane);
        s = wredsum(s);
        if (lane == 0) cstore(&d_g2[wid], s + b2);
      }
      if (jB >= 0) {
        float s = wredsum(dotp(Vw1 + (size_t)jB * HD, s0, HD, lane));
        if (lane == 0) cstore(&d_z1[jB], s + vbB);
      }
    }
    gbar(ep);

    // ======== ROUND C: cell2 ; g3 = M3@TD2n + Whh3@h3 ; rec2 ===============
    {
      if (tid < 512) {
        int j = tid * 2;
        float2 gi = cload2(&d_g2[j]),        gf = cload2(&d_g2[j + HD]);
        float2 gg = cload2(&d_g2[j + 2*HD]), go = cload2(&d_g2[j + 3*HD]);
        float2 cp = cload2(&d_c2[cur][j]);
        float2 rc = cload2(&d_rec3[cur][j]);
        float cA = sigf(gf.x) * cp.x + sigf(gi.x) * tanhfast(gg.x);
        float cB = sigf(gf.y) * cp.y + sigf(gi.y) * tanhfast(gg.y);
        float hA = sigf(go.x) * tanhfast(cA);
        float hB = sigf(go.y) * tanhfast(cB);
        float tA = hA - rc.x, tB = hB - rc.y;
        s0[j] = hA; s0[j + 1] = hB;
        s1[j] = tA; s1[j + 1] = tB;
        *(float2*)(s3 + j) = cload2(&d_h3[cur][j]);
        if ((tid >> 1) == bid) {
          cstore2(&d_h2[nxt][j], hA, hB); cstore2(&d_c2[nxt][j], cA, cB);
          cstore2(&d_TD2[nxt][j], tA, tB);
        }
      }
      __syncthreads();
      if (w0) {
        float a = 0.f;
        #pragma unroll
        for (int k = 0; k < 16; ++k) a += fabsf(s1[tid + 64 * k]);
        a = wredsum(a);
        if (tid == 0) loss_acc += (LAMF * LAMF) * a;
      }
      {
        float s = dotp(d_M3 + (size_t)wid * HD, s1, HD, lane)
                + dotp(Whh3 + (size_t)wid * HD, s3, HD, lane);
        s = wredsum(s);
        if (lane == 0) cstore(&d_g3[wid], s + b3);
      }
      if (jA >= 0) {
        float s = wredsum(dotp(Vw2 + (size_t)jA * HD, s0, HD, lane));
        if (lane == 0) cstore(&d_rec2[nxt][jA], s + vbC);
      }
    }
    gbar(ep);
  }

  // epilogue: predictions[TT-1] = softmax(z1 of last step) ; scalars
  if (w0) {
    float2 za = cload2(&d_z1[tid * 4]), zb = cload2(&d_z1[tid * 4 + 2]);
    float m = wredmax(fmaxf(fmaxf(za.x, za.y), fmaxf(zb.x, zb.y)));
    float e0 = __expf(za.x - m), e1 = __expf(za.y - m);
    float e2 = __expf(zb.x - m), e3 = __expf(zb.y - m);
    float inv = 1.f / wredsum((e0 + e1) + (e2 + e3));
    float* po = out + 2 + (size_t)(TT - 1) * CD + tid * 4;
    po[0] = e0 * inv; po[1] = e1 * inv; po[2] = e2 * inv; po[3] = e3 * inv;
    if (tid == 0) { out[0] = loss_acc; out[1] = fll_acc; }
  }
}

extern "C" void kernel_launch(void* const* d_in, const int* in_sizes, int n_in,
                              void* d_out, int out_size, void* d_ws, size_t ws_size,
                              hipStream_t stream) {
  const float* x    = (const float*)d_in[0];
  const float* Wih1 = (const float*)d_in[1];
  const float* Whh1 = (const float*)d_in[2];
  const float* bih1 = (const float*)d_in[3];
  const float* bhh1 = (const float*)d_in[4];
  const float* Vw1  = (const float*)d_in[5];
  const float* Vb1  = (const float*)d_in[6];
  const float* Wih2 = (const float*)d_in[7];
  const float* Whh2 = (const float*)d_in[8];
  const float* bih2 = (const float*)d_in[9];
  const float* bhh2 = (const float*)d_in[10];
  const float* Vw2  = (const float*)d_in[11];
  const float* Vb2  = (const float*)d_in[12];
  const float* Wih3 = (const float*)d_in[13];
  const float* Whh3 = (const float*)d_in[14];
  const float* bih3 = (const float*)d_in[15];
  const float* bhh3 = (const float*)d_in[16];
  const float* Vw3  = (const float*)d_in[17];
  const float* Vb3  = (const float*)d_in[18];
  const float* Ww0  = (const float*)d_in[19];
  const float* Wb0  = (const float*)d_in[20];
  const float* Ww1  = (const float*)d_in[21];
  const float* Wb1  = (const float*)d_in[22];
  const float* Ww2  = (const float*)d_in[23];
  const float* Wb2  = (const float*)d_in[24];
  const float* r1   = (const float*)d_in[25];
  const float* r2   = (const float*)d_in[26];
  const float* r3   = (const float*)d_in[27];

  pc_fold<<<2304, 256, 0, stream>>>(Wih1, Wih2, Wih3, Ww0, Ww1, Ww2);
  pc_init<<<1, NWG, 0, stream>>>();
  pc_main<<<NWG, NTH, 0, stream>>>(x, Wih1, Whh1, bih1, bhh1, Vw1, Vb1,
                                   Wih2, Whh2, bih2, bhh2, Vw2, Vb2,
                                   Wih3, Whh3, bih3, bhh3, Vw3, Vb3,
                                   Ww0, Wb0, Ww1, Wb1, Ww2, Wb2,
                                   r1, r2, r3, (float*)d_out);
}

// Round 7
// 19524.670 us; speedup vs baseline: 3.1863x; 1.2055x over previous
//
#include <hip/hip_runtime.h>
#include <math.h>

#define HD 1024
#define CD 256
#define TT 512
#define GD 4096                 // 4*H
#define NWG 256
#define NTH 1024
#define WPB 16                  // waves per block
#define NWAVE (NWG*WPB)         // 4096
#define LAMF 0.05f

typedef unsigned long long ull;

// ---------------- folded matrices (computed by pc_fold every call) --------
__device__ __align__(16) float d_M1[GD * CD];   //  4 MB : Wih1[:,:H] @ Ww0
__device__ __align__(16) float d_M2[GD * HD];   // 16 MB : Wih2[:,:H] @ Ww1
__device__ __align__(16) float d_M3[GD * HD];   // 16 MB : Wih3      @ Ww2

// ---------------- cross-WG vectors (only matvec outputs are published) ----
__device__ __align__(16) float d_g1[GD], d_g2[GD], d_g3[GD];
__device__ __align__(16) float d_z1[CD];
__device__ __align__(16) float d_rec2[HD], d_rec3[HD];
__device__ int d_arr[NWG][32];
__device__ int d_rel;

__global__ void pc_init() { d_arr[threadIdx.x][0] = 0; if (threadIdx.x == 0) d_rel = 0; }

__device__ __forceinline__ float sigf(float x)     { return 1.f / (1.f + __expf(-x)); }
__device__ __forceinline__ float tanhfast(float x) { return 1.f - 2.f / (1.f + __expf(2.f * x)); }

__device__ __forceinline__ float cload(const float* p) {
  return __hip_atomic_load(p, __ATOMIC_RELAXED, __HIP_MEMORY_SCOPE_AGENT);
}
__device__ __forceinline__ void cstore(float* p, float v) {
  __hip_atomic_store(p, v, __ATOMIC_RELAXED, __HIP_MEMORY_SCOPE_AGENT);
}
__device__ __forceinline__ float2 cload2(const float* p) {
  union { ull u; float2 f; } c;
  c.u = __hip_atomic_load((const ull*)p, __ATOMIC_RELAXED, __HIP_MEMORY_SCOPE_AGENT);
  return c.f;
}

// Distributed epoch barrier (R3-proven; no cache-invalidating fences).
__device__ __forceinline__ void gbar(int& ep) {
  ++ep;
  __syncthreads();
  const int tid = threadIdx.x;
  if (blockIdx.x == 0) {
    if (tid >= 1 && tid < NWG) {
      while (__hip_atomic_load(&d_arr[tid][0], __ATOMIC_RELAXED, __HIP_MEMORY_SCOPE_AGENT) < ep)
        __builtin_amdgcn_s_sleep(1);
    }
    __syncthreads();
    if (tid == 0)
      __hip_atomic_store(&d_rel, ep, __ATOMIC_RELEASE, __HIP_MEMORY_SCOPE_AGENT);
  } else {
    if (tid == 0) {
      __hip_atomic_store(&d_arr[blockIdx.x][0], ep, __ATOMIC_RELEASE, __HIP_MEMORY_SCOPE_AGENT);
      while (__hip_atomic_load(&d_rel, __ATOMIC_RELAXED, __HIP_MEMORY_SCOPE_AGENT) < ep)
        __builtin_amdgcn_s_sleep(1);
    }
    __syncthreads();
  }
}

__device__ __forceinline__ float wredsum(float v) {
  #pragma unroll
  for (int off = 32; off; off >>= 1) v += __shfl_xor(v, off);
  return v;
}
__device__ __forceinline__ float wredmax(float v) {
  #pragma unroll
  for (int off = 32; off; off >>= 1) v = fmaxf(v, __shfl_xor(v, off));
  return v;
}

// per-lane partial dot of one weight row against an LDS vector (n % 256 == 0)
__device__ __forceinline__ float dotp(const float* __restrict__ w, const float* xv, int n, int lane) {
  float a0 = 0.f, a1 = 0.f, a2 = 0.f, a3 = 0.f;
  for (int c = lane * 4; c < n; c += 256) {
    const float4 wv = *(const float4*)(w + c);
    const float4 vv = *(const float4*)(xv + c);
    a0 = fmaf(wv.x, vv.x, a0);
    a1 = fmaf(wv.y, vv.y, a1);
    a2 = fmaf(wv.z, vv.z, a2);
    a3 = fmaf(wv.w, vv.w, a3);
  }
  return (a0 + a1) + (a2 + a3);
}

// ---------------- fold GEMM: C[4096 x N] = A[4096 x 1024] @ B[1024 x N] ----
__global__ __launch_bounds__(256) void pc_fold(
    const float* __restrict__ Wih1, const float* __restrict__ Wih2,
    const float* __restrict__ Wih3, const float* __restrict__ Ww0,
    const float* __restrict__ Ww1,  const float* __restrict__ Ww2) {
  int b = blockIdx.x;
  const float* A; const float* B; float* C; int N, lda;
  if (b < 256)        { A = Wih1; B = Ww0; C = d_M1; N = CD; lda = 2 * HD; }
  else if (b < 1280)  { A = Wih2; B = Ww1; C = d_M2; N = HD; lda = 2 * HD; b -= 256; }
  else                { A = Wih3; B = Ww2; C = d_M3; N = HD; lda = HD;     b -= 1280; }
  const int ctiles = N >> 6;
  const int rt = b / ctiles, ct = b - rt * ctiles;
  const int tid = threadIdx.x;
  const int tx = tid & 15, ty = tid >> 4;

  __shared__ float sA[16][65];
  __shared__ float sB[16][64];

  float acc[4][4] = {};
  const int ar = tid >> 2, aq = tid & 3;
  const int br = tid >> 4, bq = tid & 15;

  for (int kk = 0; kk < HD; kk += 16) {
    float4 av = *(const float4*)(A + (size_t)(rt * 64 + ar) * lda + kk + aq * 4);
    float4 bv = *(const float4*)(B + (size_t)(kk + br) * N + ct * 64 + bq * 4);
    __syncthreads();
    sA[aq * 4 + 0][ar] = av.x; sA[aq * 4 + 1][ar] = av.y;
    sA[aq * 4 + 2][ar] = av.z; sA[aq * 4 + 3][ar] = av.w;
    *(float4*)&sB[br][bq * 4] = bv;
    __syncthreads();
    #pragma unroll
    for (int k = 0; k < 16; ++k) {
      const float4 b4 = *(const float4*)&sB[k][tx * 4];
      const float a0 = sA[k][ty * 4 + 0], a1 = sA[k][ty * 4 + 1];
      const float a2 = sA[k][ty * 4 + 2], a3 = sA[k][ty * 4 + 3];
      acc[0][0] = fmaf(a0, b4.x, acc[0][0]); acc[0][1] = fmaf(a0, b4.y, acc[0][1]);
      acc[0][2] = fmaf(a0, b4.z, acc[0][2]); acc[0][3] = fmaf(a0, b4.w, acc[0][3]);
      acc[1][0] = fmaf(a1, b4.x, acc[1][0]); acc[1][1] = fmaf(a1, b4.y, acc[1][1]);
      acc[1][2] = fmaf(a1, b4.z, acc[1][2]); acc[1][3] = fmaf(a1, b4.w, acc[1][3]);
      acc[2][0] = fmaf(a2, b4.x, acc[2][0]); acc[2][1] = fmaf(a2, b4.y, acc[2][1]);
      acc[2][2] = fmaf(a2, b4.z, acc[2][2]); acc[2][3] = fmaf(a2, b4.w, acc[2][3]);
      acc[3][0] = fmaf(a3, b4.x, acc[3][0]); acc[3][1] = fmaf(a3, b4.y, acc[3][1]);
      acc[3][2] = fmaf(a3, b4.z, acc[3][2]); acc[3][3] = fmaf(a3, b4.w, acc[3][3]);
    }
  }
  #pragma unroll
  for (int i = 0; i < 4; ++i) {
    float4 r = make_float4(acc[i][0], acc[i][1], acc[i][2], acc[i][3]);
    *(float4*)(C + (size_t)(rt * 64 + ty * 4 + i) * N + ct * 64 + tx * 4) = r;
  }
}

__global__ __launch_bounds__(NTH, 1) void pc_main(
    const float* __restrict__ x,
    const float* __restrict__ Wih1, const float* __restrict__ Whh1,
    const float* __restrict__ bih1, const float* __restrict__ bhh1,
    const float* __restrict__ Vw1,  const float* __restrict__ Vb1,
    const float* __restrict__ Wih2, const float* __restrict__ Whh2,
    const float* __restrict__ bih2, const float* __restrict__ bhh2,
    const float* __restrict__ Vw2,  const float* __restrict__ Vb2,
    const float* __restrict__ Wih3, const float* __restrict__ Whh3,
    const float* __restrict__ bih3, const float* __restrict__ bhh3,
    const float* __restrict__ Vw3,  const float* __restrict__ Vb3,
    const float* __restrict__ Ww0,  const float* __restrict__ Wb0,
    const float* __restrict__ Ww1,  const float* __restrict__ Wb1,
    const float* __restrict__ Ww2,  const float* __restrict__ Wb2,
    const float* __restrict__ r1,   const float* __restrict__ r2,
    const float* __restrict__ r3,
    float* __restrict__ out) {
  const int tid  = threadIdx.x;
  const int lane = tid & 63;
  const int bid  = blockIdx.x;
  const int wid  = bid * WPB + (tid >> 6);
  const bool iswg0 = (bid == 0);
  const bool w0    = iswg0 && tid < 64;

  // per-WG local full state (never published)
  __shared__ __align__(16) float s_h1[HD], s_TD1[HD], s_h2[HD], s_TD2[HD], s_h3[HD];
  __shared__ __align__(16) float s_c1[HD], s_c2[HD], s_c3[HD];
  __shared__ __align__(16) float s_small[CD];   // TD0 of the step being fed to g1

  // rotated element index for cell work (spreads coherent-line traffic)
  const int e = (tid < 512) ? (((tid + (bid << 3)) & 511) * 2) : 0;

  // secondary matvec jobs
  const int jR = ((wid & 3) == 1)  ? (wid >> 2) : -1;   // rec3 (P) / rec2 (Q)
  const int jZ = ((wid & 15) == 2) ? (wid >> 4) : -1;   // z1 (P)

  int ep = 0;
  float loss_acc = 0.f, fll_acc = 0.f;
  float b1, b2, b3, vbR3 = 0.f, vbR2 = 0.f, vbZ = 0.f;

  // ---------------- prologue: fold biases, init state, g1(0) ---------------
  if (tid < 512) {
    int j = tid * 2;
    *(float2*)(s_h1 + j) = *(const float2*)(Wb0 + j);
    *(float2*)(s_c1 + j) = *(const float2*)(Wb1 + j);
    *(float2*)(s_c2 + j) = *(const float2*)(Wb2 + j);
  }
  __syncthreads();
  b1 = bih1[wid] + bhh1[wid] + wredsum(dotp(Wih1 + (size_t)wid * 2 * HD, s_h1, HD, lane));
  b2 = bih2[wid] + bhh2[wid] + wredsum(dotp(Wih2 + (size_t)wid * 2 * HD, s_c1, HD, lane));
  b3 = bih3[wid] + bhh3[wid] + wredsum(dotp(Wih3 + (size_t)wid * HD,     s_c2, HD, lane));
  if (jR >= 0) { vbR3 = Vb3[jR]; vbR2 = Vb2[jR]; }
  if (jZ >= 0) vbZ = Vb1[jZ];
  __syncthreads();
  if (tid < 512) {
    int j = tid * 2;
    const float2 z2 = make_float2(0.f, 0.f);
    *(float2*)(s_h2 + j) = z2; *(float2*)(s_TD2 + j) = z2; *(float2*)(s_h3 + j) = z2;
    *(float2*)(s_c1 + j) = z2; *(float2*)(s_c2 + j) = z2; *(float2*)(s_c3 + j) = z2;
  }
  if (tid < 64) {                       // softmax(r1) -> TD0(0); loss0(0)
    float4 z4 = *(const float4*)(r1 + tid * 4);
    float m = wredmax(fmaxf(fmaxf(z4.x, z4.y), fmaxf(z4.z, z4.w)));
    float e0 = __expf(z4.x - m), e1 = __expf(z4.y - m);
    float e2 = __expf(z4.z - m), e3 = __expf(z4.w - m);
    float inv = 1.f / wredsum((e0 + e1) + (e2 + e3));
    float p0 = e0 * inv, p1 = e1 * inv, p2 = e2 * inv, p3 = e3 * inv;
    float4 xv = *(const float4*)(x + tid * 4);
    s_small[tid * 4 + 0] = xv.x - p0; s_small[tid * 4 + 1] = xv.y - p1;
    s_small[tid * 4 + 2] = xv.z - p2; s_small[tid * 4 + 3] = xv.w - p3;
    if (iswg0) {
      float u = xv.x * __logf(p0) + (1.f - xv.x) * __logf(1.f - p0)
              + xv.y * __logf(p1) + (1.f - xv.y) * __logf(1.f - p1)
              + xv.z * __logf(p2) + (1.f - xv.z) * __logf(1.f - p2)
              + xv.w * __logf(p3) + (1.f - xv.w) * __logf(1.f - p3);
      u = wredsum(u);
      if (tid == 0) { loss_acc -= u; fll_acc -= u; }
    }
  }
  __syncthreads();
  {                                     // g1(0) = M1@TD0(0) + b1
    float s = wredsum(dotp(d_M1 + (size_t)wid * CD, s_small, CD, lane));
    if (lane == 0) cstore(&d_g1[wid], s + b1);
  }
  gbar(ep);

  for (int t = 0; t < TT; ++t) {
    // ========== P(t): cell3(t-1), cell1(t) ; g2(t), z1(t), rec3(t-1) ======
    if (tid < 512) {
      if (t > 0) {                      // cell3(t-1)
        float2 gi = cload2(&d_g3[e]),          gf = cload2(&d_g3[e + HD]);
        float2 gg = cload2(&d_g3[e + 2 * HD]), go = cload2(&d_g3[e + 3 * HD]);
        float cA = sigf(gf.x) * s_c3[e]     + sigf(gi.x) * tanhfast(gg.x);
        float cB = sigf(gf.y) * s_c3[e + 1] + sigf(gi.y) * tanhfast(gg.y);
        float hA = sigf(go.x) * tanhfast(cA);
        float hB = sigf(go.y) * tanhfast(cB);
        s_c3[e] = cA; s_c3[e + 1] = cB; s_h3[e] = hA; s_h3[e + 1] = hB;
      }
      {                                 // cell1(t)
        float2 gi = cload2(&d_g1[e]),          gf = cload2(&d_g1[e + HD]);
        float2 gg = cload2(&d_g1[e + 2 * HD]), go = cload2(&d_g1[e + 3 * HD]);
        float2 rc = (t == 0) ? *(const float2*)(r2 + e) : cload2(&d_rec2[e]);
        float cA = sigf(gf.x) * s_c1[e]     + sigf(gi.x) * tanhfast(gg.x);
        float cB = sigf(gf.y) * s_c1[e + 1] + sigf(gi.y) * tanhfast(gg.y);
        float hA = sigf(go.x) * tanhfast(cA);
        float hB = sigf(go.y) * tanhfast(cB);
        s_c1[e] = cA; s_c1[e + 1] = cB; s_h1[e] = hA; s_h1[e + 1] = hB;
        s_TD1[e] = hA - rc.x; s_TD1[e + 1] = hB - rc.y;
      }
    }
    __syncthreads();
    if (w0) {                           // LAM * sum|TD1(t)|
      float a = 0.f;
      #pragma unroll
      for (int k = 0; k < 16; ++k) a += fabsf(s_TD1[tid + 64 * k]);
      a = wredsum(a);
      if (tid == 0) loss_acc += LAMF * a;
    }
    {                                   // g2(t)
      float s = dotp(d_M2 + (size_t)wid * HD, s_TD1, HD, lane)
              + dotp(Wih2 + (size_t)wid * 2 * HD + HD, s_TD2, HD, lane)
              + dotp(Whh2 + (size_t)wid * HD, s_h2, HD, lane);
      s = wredsum(s);
      if (lane == 0) cstore(&d_g2[wid], s + b2);
    }
    if (t > 0 && jR >= 0) {             // rec3(t-1) = Vw3 @ h3(t-1)
      float s = wredsum(dotp(Vw3 + (size_t)jR * HD, s_h3, HD, lane));
      if (lane == 0) cstore(&d_rec3[jR], s + vbR3);
    }
    if (jZ >= 0) {                      // z1(t) = Vw1 @ h1(t)
      float s = wredsum(dotp(Vw1 + (size_t)jZ * HD, s_h1, HD, lane));
      if (lane == 0) cstore(&d_z1[jZ], s + vbZ);
    }
    gbar(ep);

    // ========== Q(t): cell2(t), softmax(z1) ; g3(t), g1(t+1), rec2(t) =====
    if (tid < 512) {                    // cell2(t)
      float2 gi = cload2(&d_g2[e]),          gf = cload2(&d_g2[e + HD]);
      float2 gg = cload2(&d_g2[e + 2 * HD]), go = cload2(&d_g2[e + 3 * HD]);
      float2 rc = (t == 0) ? *(const float2*)(r3 + e) : cload2(&d_rec3[e]);
      float cA = sigf(gf.x) * s_c2[e]     + sigf(gi.x) * tanhfast(gg.x);
      float cB = sigf(gf.y) * s_c2[e + 1] + sigf(gi.y) * tanhfast(gg.y);
      float hA = sigf(go.x) * tanhfast(cA);
      float hB = sigf(go.y) * tanhfast(cB);
      s_c2[e] = cA; s_c2[e + 1] = cB; s_h2[e] = hA; s_h2[e + 1] = hB;
      s_TD2[e] = hA - rc.x; s_TD2[e + 1] = hB - rc.y;
    }
    if (tid < 64) {                     // softmax(z1(t)) -> predictions[t], TD0(t+1)
      float2 za = cload2(&d_z1[tid * 4]), zb = cload2(&d_z1[tid * 4 + 2]);
      float m = wredmax(fmaxf(fmaxf(za.x, za.y), fmaxf(zb.x, zb.y)));
      float e0 = __expf(za.x - m), e1 = __expf(za.y - m);
      float e2 = __expf(zb.x - m), e3 = __expf(zb.y - m);
      float inv = 1.f / wredsum((e0 + e1) + (e2 + e3));
      float p0 = e0 * inv, p1 = e1 * inv, p2 = e2 * inv, p3 = e3 * inv;
      if (t < TT - 1) {
        float4 xv = *(const float4*)(x + (size_t)(t + 1) * CD + tid * 4);
        s_small[tid * 4 + 0] = xv.x - p0; s_small[tid * 4 + 1] = xv.y - p1;
        s_small[tid * 4 + 2] = xv.z - p2; s_small[tid * 4 + 3] = xv.w - p3;
        if (iswg0) {                    // loss0(t+1)
          float u = xv.x * __logf(p0) + (1.f - xv.x) * __logf(1.f - p0)
                  + xv.y * __logf(p1) + (1.f - xv.y) * __logf(1.f - p1)
                  + xv.z * __logf(p2) + (1.f - xv.z) * __logf(1.f - p2)
                  + xv.w * __logf(p3) + (1.f - xv.w) * __logf(1.f - p3);
          u = wredsum(u);
          if (tid == 0) { loss_acc -= u; fll_acc -= u; }
        }
      }
      if (iswg0) {                      // predictions[t] = softmax(z1(t))
        float* po = out + 2 + (size_t)t * CD + tid * 4;
        po[0] = p0; po[1] = p1; po[2] = p2; po[3] = p3;
      }
    }
    __syncthreads();
    if (w0) {                           // LAM^2 * sum|TD2(t)|
      float a = 0.f;
      #pragma unroll
      for (int k = 0; k < 16; ++k) a += fabsf(s_TD2[tid + 64 * k]);
      a = wredsum(a);
      if (tid == 0) loss_acc += (LAMF * LAMF) * a;
    }
    if (t < TT - 1) {
      {                                 // g3(t)
        float s = dotp(d_M3 + (size_t)wid * HD, s_TD2, HD, lane)
                + dotp(Whh3 + (size_t)wid * HD, s_h3, HD, lane);
        s = wredsum(s);
        if (lane == 0) cstore(&d_g3[wid], s + b3);
      }
      {                                 // g1(t+1)
        float s = dotp(d_M1 + (size_t)wid * CD, s_small, CD, lane)
                + dotp(Wih1 + (size_t)wid * 2 * HD + HD, s_TD1, HD, lane)
                + dotp(Whh1 + (size_t)wid * HD, s_h1, HD, lane);
        s = wredsum(s);
        if (lane == 0) cstore(&d_g1[wid], s + b1);
      }
      if (jR >= 0) {                    // rec2(t) = Vw2 @ h2(t)
        float s = wredsum(dotp(Vw2 + (size_t)jR * HD, s_h2, HD, lane));
        if (lane == 0) cstore(&d_rec2[jR], s + vbR2);
      }
      gbar(ep);
    }
  }

  if (iswg0 && tid == 0) { out[0] = loss_acc; out[1] = fll_acc; }
}

extern "C" void kernel_launch(void* const* d_in, const int* in_sizes, int n_in,
                              void* d_out, int out_size, void* d_ws, size_t ws_size,
                              hipStream_t stream) {
  const float* x    = (const float*)d_in[0];
  const float* Wih1 = (const float*)d_in[1];
  const float* Whh1 = (const float*)d_in[2];
  const float* bih1 = (const float*)d_in[3];
  const float* bhh1 = (const float*)d_in[4];
  const float* Vw1  = (const float*)d_in[5];
  const float* Vb1  = (const float*)d_in[6];
  const float* Wih2 = (const float*)d_in[7];
  const float* Whh2 = (const float*)d_in[8];
  const float* bih2 = (const float*)d_in[9];
  const float* bhh2 = (const float*)d_in[10];
  const float* Vw2  = (const float*)d_in[11];
  const float* Vb2  = (const float*)d_in[12];
  const float* Wih3 = (const float*)d_in[13];
  const float* Whh3 = (const float*)d_in[14];
  const float* bih3 = (const float*)d_in[15];
  const float* bhh3 = (const float*)d_in[16];
  const float* Vw3  = (const float*)d_in[17];
  const float* Vb3  = (const float*)d_in[18];
  const float* Ww0  = (const float*)d_in[19];
  const float* Wb0  = (const float*)d_in[20];
  const float* Ww1  = (const float*)d_in[21];
  const float* Wb1  = (const float*)d_in[22];
  const float* Ww2  = (const float*)d_in[23];
  const float* Wb2  = (const float*)d_in[24];
  const float* r1   = (const float*)d_in[25];
  const float* r2   = (const float*)d_in[26];
  const float* r3   = (const float*)d_in[27];

  pc_fold<<<2304, 256, 0, stream>>>(Wih1, Wih2, Wih3, Ww0, Ww1, Ww2);
  pc_init<<<1, NWG, 0, stream>>>();
  pc_main<<<NWG, NTH, 0, stream>>>(x, Wih1, Whh1, bih1, bhh1, Vw1, Vb1,
                                   Wih2, Whh2, bih2, bhh2, Vw2, Vb2,
                                   Wih3, Whh3, bih3, bhh3, Vw3, Vb3,
                                   Ww0, Wb0, Ww1, Wb1, Ww2, Wb2,
                                   r1, r2, r3, (float*)d_out);
}

// Round 8
// 10944.228 us; speedup vs baseline: 5.6845x; 1.7840x over previous
//
#include <hip/hip_runtime.h>
#include <math.h>

#define HD 1024
#define CD 256
#define TT 512
#define GD 4096                 // 4*H
#define NWG 256
#define NTH 1024
#define WPB 16                  // waves per block
#define NWAVE (NWG*WPB)         // 4096
#define LAMF 0.05f

typedef unsigned long long ull;
typedef unsigned short ushortt;
typedef _Float16 hh2 __attribute__((ext_vector_type(2)));

// ---------------- fp16 weight copies (built per call) ---------------------
__device__ __align__(16) ushortt hM1[GD * CD];    //  2 MB : Wih1[:,:H]@Ww0
__device__ __align__(16) ushortt hM2[GD * HD];    //  8 MB : Wih2[:,:H]@Ww1
__device__ __align__(16) ushortt hM3[GD * HD];    //  8 MB : Wih3@Ww2
__device__ __align__(16) ushortt hW1b[GD * HD];   //  8 MB : Wih1[:,H:]
__device__ __align__(16) ushortt hWhh1[GD * HD];  //  8 MB
__device__ __align__(16) ushortt hW2b[GD * HD];   //  8 MB : Wih2[:,H:]
__device__ __align__(16) ushortt hWhh2[GD * HD];  //  8 MB
__device__ __align__(16) ushortt hWhh3[GD * HD];  //  8 MB
__device__ __align__(16) ushortt hVw1[CD * HD];   // .5 MB
__device__ __align__(16) ushortt hVw2[HD * HD];   //  2 MB
__device__ __align__(16) ushortt hVw3[HD * HD];   //  2 MB

// ---------------- cross-WG vectors (only matvec outputs are published) ----
__device__ __align__(16) float d_g1[GD], d_g2[GD], d_g3[GD];
__device__ __align__(16) float d_z1[CD];
__device__ __align__(16) float d_rec2[HD], d_rec3[HD];
__device__ int d_arr[NWG][32];
__device__ int d_rel;

__global__ void pc_init() { d_arr[threadIdx.x][0] = 0; if (threadIdx.x == 0) d_rel = 0; }

__device__ __forceinline__ float sigf(float x)     { return 1.f / (1.f + __expf(-x)); }
__device__ __forceinline__ float tanhfast(float x) { return 1.f - 2.f / (1.f + __expf(2.f * x)); }

__device__ __forceinline__ ushortt f2h(float x) {
  union { ushortt u; _Float16 h; } c; c.h = (_Float16)x; return c.u;
}
__device__ __forceinline__ float h2f(ushortt u) {
  union { ushortt u; _Float16 h; } c; c.u = u; return (float)c.h;
}
__device__ __forceinline__ unsigned packh2(float a, float b) {
  union { unsigned u; hh2 h; } c; c.h = hh2{(_Float16)a, (_Float16)b}; return c.u;
}
__device__ __forceinline__ float fd2(unsigned a, unsigned b, float c) {
  union { unsigned u; hh2 h; } ua, ub; ua.u = a; ub.u = b;
  return __builtin_amdgcn_fdot2(ua.h, ub.h, c, false);
}

__device__ __forceinline__ float cload(const float* p) {
  return __hip_atomic_load(p, __ATOMIC_RELAXED, __HIP_MEMORY_SCOPE_AGENT);
}
__device__ __forceinline__ void cstore(float* p, float v) {
  __hip_atomic_store(p, v, __ATOMIC_RELAXED, __HIP_MEMORY_SCOPE_AGENT);
}
__device__ __forceinline__ float2 cload2(const float* p) {
  union { ull u; float2 f; } c;
  c.u = __hip_atomic_load((const ull*)p, __ATOMIC_RELAXED, __HIP_MEMORY_SCOPE_AGENT);
  return c.f;
}

// Distributed epoch barrier (R3-proven; no cache-invalidating fences).
__device__ __forceinline__ void gbar(int& ep) {
  ++ep;
  __syncthreads();
  const int tid = threadIdx.x;
  if (blockIdx.x == 0) {
    if (tid >= 1 && tid < NWG) {
      while (__hip_atomic_load(&d_arr[tid][0], __ATOMIC_RELAXED, __HIP_MEMORY_SCOPE_AGENT) < ep)
        __builtin_amdgcn_s_sleep(1);
    }
    __syncthreads();
    if (tid == 0)
      __hip_atomic_store(&d_rel, ep, __ATOMIC_RELEASE, __HIP_MEMORY_SCOPE_AGENT);
  } else {
    if (tid == 0) {
      __hip_atomic_store(&d_arr[blockIdx.x][0], ep, __ATOMIC_RELEASE, __HIP_MEMORY_SCOPE_AGENT);
      while (__hip_atomic_load(&d_rel, __ATOMIC_RELAXED, __HIP_MEMORY_SCOPE_AGENT) < ep)
        __builtin_amdgcn_s_sleep(1);
    }
    __syncthreads();
  }
}

__device__ __forceinline__ float wredsum(float v) {
  #pragma unroll
  for (int off = 32; off; off >>= 1) v += __shfl_xor(v, off);
  return v;
}
__device__ __forceinline__ float wredmax(float v) {
  #pragma unroll
  for (int off = 32; off; off >>= 1) v = fmaxf(v, __shfl_xor(v, off));
  return v;
}

// fp32 dot (prologue only)
__device__ __forceinline__ float dotp(const float* __restrict__ w, const float* xv, int n, int lane) {
  float a0 = 0.f, a1 = 0.f, a2 = 0.f, a3 = 0.f;
  for (int c = lane * 4; c < n; c += 256) {
    const float4 wv = *(const float4*)(w + c);
    const float4 vv = *(const float4*)(xv + c);
    a0 = fmaf(wv.x, vv.x, a0); a1 = fmaf(wv.y, vv.y, a1);
    a2 = fmaf(wv.z, vv.z, a2); a3 = fmaf(wv.w, vv.w, a3);
  }
  return (a0 + a1) + (a2 + a3);
}

// fp16 dot over 1024 halves (weight row in global, vector in LDS)
__device__ __forceinline__ float dotH(const ushortt* __restrict__ w, const ushortt* xv, int lane) {
  const uint4 w0 = *(const uint4*)(w + lane * 8);
  const uint4 w1 = *(const uint4*)(w + lane * 8 + 512);
  const uint4 v0 = *(const uint4*)(xv + lane * 8);
  const uint4 v1 = *(const uint4*)(xv + lane * 8 + 512);
  float a = 0.f;
  a = fd2(w0.x, v0.x, a); a = fd2(w0.y, v0.y, a);
  a = fd2(w0.z, v0.z, a); a = fd2(w0.w, v0.w, a);
  a = fd2(w1.x, v1.x, a); a = fd2(w1.y, v1.y, a);
  a = fd2(w1.z, v1.z, a); a = fd2(w1.w, v1.w, a);
  return a;
}
// fp16 dot over 256 halves
__device__ __forceinline__ float dotH256(const ushortt* __restrict__ w, const ushortt* xv, int lane) {
  const uint2 wv = *(const uint2*)(w + lane * 4);
  const uint2 vv = *(const uint2*)(xv + lane * 4);
  float a = fd2(wv.x, vv.x, 0.f);
  return fd2(wv.y, vv.y, a);
}

// ---------------- fp32->fp16 weight conversion ----------------------------
__global__ __launch_bounds__(256) void pc_conv(
    const float* __restrict__ Wih1, const float* __restrict__ Whh1,
    const float* __restrict__ Wih2, const float* __restrict__ Whh2,
    const float* __restrict__ Whh3, const float* __restrict__ Vw1,
    const float* __restrict__ Vw2,  const float* __restrict__ Vw3) {
  const size_t stride = (size_t)gridDim.x * 256;
  const size_t i0 = (size_t)blockIdx.x * 256 + threadIdx.x;
  for (size_t i = i0; i < (size_t)GD * HD; i += stride) {
    size_t r = i >> 10, c = i & 1023;
    size_t src = (r << 11) + HD + c;
    hW1b[i]  = f2h(Wih1[src]);
    hW2b[i]  = f2h(Wih2[src]);
    hWhh1[i] = f2h(Whh1[i]);
    hWhh2[i] = f2h(Whh2[i]);
    hWhh3[i] = f2h(Whh3[i]);
  }
  for (size_t i = i0; i < (size_t)HD * HD; i += stride) {
    hVw2[i] = f2h(Vw2[i]);
    hVw3[i] = f2h(Vw3[i]);
  }
  for (size_t i = i0; i < (size_t)CD * HD; i += stride) hVw1[i] = f2h(Vw1[i]);
}

// ---------------- fold GEMM: fp16 C[4096 x N] = A @ B ---------------------
__global__ __launch_bounds__(256) void pc_fold(
    const float* __restrict__ Wih1, const float* __restrict__ Wih2,
    const float* __restrict__ Wih3, const float* __restrict__ Ww0,
    const float* __restrict__ Ww1,  const float* __restrict__ Ww2) {
  int b = blockIdx.x;
  const float* A; const float* B; ushortt* C; int N, lda;
  if (b < 256)        { A = Wih1; B = Ww0; C = hM1; N = CD; lda = 2 * HD; }
  else if (b < 1280)  { A = Wih2; B = Ww1; C = hM2; N = HD; lda = 2 * HD; b -= 256; }
  else                { A = Wih3; B = Ww2; C = hM3; N = HD; lda = HD;     b -= 1280; }
  const int ctiles = N >> 6;
  const int rt = b / ctiles, ct = b - rt * ctiles;
  const int tid = threadIdx.x;
  const int tx = tid & 15, ty = tid >> 4;

  __shared__ float sA[16][65];
  __shared__ float sB[16][64];

  float acc[4][4] = {};
  const int ar = tid >> 2, aq = tid & 3;
  const int br = tid >> 4, bq = tid & 15;

  for (int kk = 0; kk < HD; kk += 16) {
    float4 av = *(const float4*)(A + (size_t)(rt * 64 + ar) * lda + kk + aq * 4);
    float4 bv = *(const float4*)(B + (size_t)(kk + br) * N + ct * 64 + bq * 4);
    __syncthreads();
    sA[aq * 4 + 0][ar] = av.x; sA[aq * 4 + 1][ar] = av.y;
    sA[aq * 4 + 2][ar] = av.z; sA[aq * 4 + 3][ar] = av.w;
    *(float4*)&sB[br][bq * 4] = bv;
    __syncthreads();
    #pragma unroll
    for (int k = 0; k < 16; ++k) {
      const float4 b4 = *(const float4*)&sB[k][tx * 4];
      const float a0 = sA[k][ty * 4 + 0], a1 = sA[k][ty * 4 + 1];
      const float a2 = sA[k][ty * 4 + 2], a3 = sA[k][ty * 4 + 3];
      acc[0][0] = fmaf(a0, b4.x, acc[0][0]); acc[0][1] = fmaf(a0, b4.y, acc[0][1]);
      acc[0][2] = fmaf(a0, b4.z, acc[0][2]); acc[0][3] = fmaf(a0, b4.w, acc[0][3]);
      acc[1][0] = fmaf(a1, b4.x, acc[1][0]); acc[1][1] = fmaf(a1, b4.y, acc[1][1]);
      acc[1][2] = fmaf(a1, b4.z, acc[1][2]); acc[1][3] = fmaf(a1, b4.w, acc[1][3]);
      acc[2][0] = fmaf(a2, b4.x, acc[2][0]); acc[2][1] = fmaf(a2, b4.y, acc[2][1]);
      acc[2][2] = fmaf(a2, b4.z, acc[2][2]); acc[2][3] = fmaf(a2, b4.w, acc[2][3]);
      acc[3][0] = fmaf(a3, b4.x, acc[3][0]); acc[3][1] = fmaf(a3, b4.y, acc[3][1]);
      acc[3][2] = fmaf(a3, b4.z, acc[3][2]); acc[3][3] = fmaf(a3, b4.w, acc[3][3]);
    }
  }
  #pragma unroll
  for (int i = 0; i < 4; ++i) {
    uint2 r = make_uint2(packh2(acc[i][0], acc[i][1]), packh2(acc[i][2], acc[i][3]));
    *(uint2*)(C + (size_t)(rt * 64 + ty * 4 + i) * N + ct * 64 + tx * 4) = r;
  }
}

__global__ __launch_bounds__(NTH, 1) void pc_main(
    const float* __restrict__ x,
    const float* __restrict__ Wih1, const float* __restrict__ Whh1,
    const float* __restrict__ bih1, const float* __restrict__ bhh1,
    const float* __restrict__ Vw1,  const float* __restrict__ Vb1,
    const float* __restrict__ Wih2, const float* __restrict__ Whh2,
    const float* __restrict__ bih2, const float* __restrict__ bhh2,
    const float* __restrict__ Vw2,  const float* __restrict__ Vb2,
    const float* __restrict__ Wih3, const float* __restrict__ Whh3,
    const float* __restrict__ bih3, const float* __restrict__ bhh3,
    const float* __restrict__ Vw3,  const float* __restrict__ Vb3,
    const float* __restrict__ Ww0,  const float* __restrict__ Wb0,
    const float* __restrict__ Ww1,  const float* __restrict__ Wb1,
    const float* __restrict__ Ww2,  const float* __restrict__ Wb2,
    const float* __restrict__ r1,   const float* __restrict__ r2,
    const float* __restrict__ r3,
    float* __restrict__ out) {
  const int tid  = threadIdx.x;
  const int lane = tid & 63;
  const int bid  = blockIdx.x;
  const int wid  = bid * WPB + (tid >> 6);
  const bool iswg0 = (bid == 0);
  const bool w0    = iswg0 && tid < 64;

  // per-WG local state: activations fp16 (matvec operands), cell states fp32
  __shared__ __align__(16) ushortt s_h1[HD], s_TD1[HD], s_h2[HD], s_TD2[HD], s_h3[HD];
  __shared__ __align__(16) float s_c1[HD], s_c2[HD], s_c3[HD];
  __shared__ __align__(16) ushortt s_small[CD];   // TD0 feeding next g1

  const int e = (tid < 512) ? (((tid + (bid << 3)) & 511) * 2) : 0;

  const int jR = ((wid & 3) == 1)  ? (wid >> 2) : -1;   // rec3 (P) / rec2 (Q)
  const int jZ = ((wid & 15) == 2) ? (wid >> 4) : -1;   // z1 (P)

  int ep = 0;
  float loss_acc = 0.f, fll_acc = 0.f;
  float b1, b2, b3, vbR3 = 0.f, vbR2 = 0.f, vbZ = 0.f;

  // ---------------- prologue: fold biases, init state, g1(0) ---------------
  if (tid < 512) {
    int j = tid * 2;
    *(float2*)(s_c1 + j) = *(const float2*)(Wb0 + j);
    *(float2*)(s_c2 + j) = *(const float2*)(Wb1 + j);
    *(float2*)(s_c3 + j) = *(const float2*)(Wb2 + j);
  }
  __syncthreads();
  b1 = bih1[wid] + bhh1[wid] + wredsum(dotp(Wih1 + (size_t)wid * 2 * HD, s_c1, HD, lane));
  b2 = bih2[wid] + bhh2[wid] + wredsum(dotp(Wih2 + (size_t)wid * 2 * HD, s_c2, HD, lane));
  b3 = bih3[wid] + bhh3[wid] + wredsum(dotp(Wih3 + (size_t)wid * HD,     s_c3, HD, lane));
  if (jR >= 0) { vbR3 = Vb3[jR]; vbR2 = Vb2[jR]; }
  if (jZ >= 0) vbZ = Vb1[jZ];
  __syncthreads();
  if (tid < 512) {
    int j = tid * 2;
    const float2 z2 = make_float2(0.f, 0.f);
    *(float2*)(s_c1 + j) = z2; *(float2*)(s_c2 + j) = z2; *(float2*)(s_c3 + j) = z2;
    *(unsigned*)(s_h1 + j) = 0u; *(unsigned*)(s_TD1 + j) = 0u;
    *(unsigned*)(s_h2 + j) = 0u; *(unsigned*)(s_TD2 + j) = 0u;
    *(unsigned*)(s_h3 + j) = 0u;
  }
  if (tid < 64) {                       // softmax(r1) -> TD0(0); loss0(0)
    float4 z4 = *(const float4*)(r1 + tid * 4);
    float m = wredmax(fmaxf(fmaxf(z4.x, z4.y), fmaxf(z4.z, z4.w)));
    float e0 = __expf(z4.x - m), e1 = __expf(z4.y - m);
    float e2 = __expf(z4.z - m), e3 = __expf(z4.w - m);
    float inv = 1.f / wredsum((e0 + e1) + (e2 + e3));
    float p0 = e0 * inv, p1 = e1 * inv, p2 = e2 * inv, p3 = e3 * inv;
    float4 xv = *(const float4*)(x + tid * 4);
    *(uint2*)(s_small + tid * 4) =
        make_uint2(packh2(xv.x - p0, xv.y - p1), packh2(xv.z - p2, xv.w - p3));
    if (iswg0) {
      float u = xv.x * __logf(p0) + (1.f - xv.x) * __logf(1.f - p0)
              + xv.y * __logf(p1) + (1.f - xv.y) * __logf(1.f - p1)
              + xv.z * __logf(p2) + (1.f - xv.z) * __logf(1.f - p2)
              + xv.w * __logf(p3) + (1.f - xv.w) * __logf(1.f - p3);
      u = wredsum(u);
      if (tid == 0) { loss_acc -= u; fll_acc -= u; }
    }
  }
  __syncthreads();
  {                                     // g1(0) = M1@TD0(0) + b1
    float s = wredsum(dotH256(hM1 + (size_t)wid * CD, s_small, lane));
    if (lane == 0) cstore(&d_g1[wid], s + b1);
  }
  gbar(ep);

  for (int t = 0; t < TT; ++t) {
    // ========== P(t): cell3(t-1), cell1(t) ; g2(t), z1(t), rec3(t-1) ======
    if (tid < 512) {
      if (t > 0) {                      // cell3(t-1)
        float2 gi = cload2(&d_g3[e]),          gf = cload2(&d_g3[e + HD]);
        float2 gg = cload2(&d_g3[e + 2 * HD]), go = cload2(&d_g3[e + 3 * HD]);
        float cA = sigf(gf.x) * s_c3[e]     + sigf(gi.x) * tanhfast(gg.x);
        float cB = sigf(gf.y) * s_c3[e + 1] + sigf(gi.y) * tanhfast(gg.y);
        float hA = sigf(go.x) * tanhfast(cA);
        float hB = sigf(go.y) * tanhfast(cB);
        s_c3[e] = cA; s_c3[e + 1] = cB;
        *(unsigned*)(s_h3 + e) = packh2(hA, hB);
      }
      {                                 // cell1(t)
        float2 gi = cload2(&d_g1[e]),          gf = cload2(&d_g1[e + HD]);
        float2 gg = cload2(&d_g1[e + 2 * HD]), go = cload2(&d_g1[e + 3 * HD]);
        float2 rc = (t == 0) ? *(const float2*)(r2 + e) : cload2(&d_rec2[e]);
        float cA = sigf(gf.x) * s_c1[e]     + sigf(gi.x) * tanhfast(gg.x);
        float cB = sigf(gf.y) * s_c1[e + 1] + sigf(gi.y) * tanhfast(gg.y);
        float hA = sigf(go.x) * tanhfast(cA);
        float hB = sigf(go.y) * tanhfast(cB);
        s_c1[e] = cA; s_c1[e + 1] = cB;
        *(unsigned*)(s_h1 + e)  = packh2(hA, hB);
        *(unsigned*)(s_TD1 + e) = packh2(hA - rc.x, hB - rc.y);
      }
    }
    __syncthreads();
    if (w0) {                           // LAM * sum|TD1(t)|
      float a = 0.f;
      #pragma unroll
      for (int k = 0; k < 16; ++k) a += fabsf(h2f(s_TD1[tid + 64 * k]));
      a = wredsum(a);
      if (tid == 0) loss_acc += LAMF * a;
    }
    {                                   // g2(t)
      float s = dotH(hM2   + (size_t)wid * HD, s_TD1, lane)
              + dotH(hW2b  + (size_t)wid * HD, s_TD2, lane)
              + dotH(hWhh2 + (size_t)wid * HD, s_h2,  lane);
      s = wredsum(s);
      if (lane == 0) cstore(&d_g2[wid], s + b2);
    }
    if (t > 0 && jR >= 0) {             // rec3(t-1) = Vw3 @ h3(t-1)
      float s = wredsum(dotH(hVw3 + (size_t)jR * HD, s_h3, lane));
      if (lane == 0) cstore(&d_rec3[jR], s + vbR3);
    }
    if (jZ >= 0) {                      // z1(t) = Vw1 @ h1(t)
      float s = wredsum(dotH(hVw1 + (size_t)jZ * HD, s_h1, lane));
      if (lane == 0) cstore(&d_z1[jZ], s + vbZ);
    }
    gbar(ep);

    // ========== Q(t): cell2(t), softmax(z1) ; g3(t), g1(t+1), rec2(t) =====
    if (tid < 512) {                    // cell2(t)
      float2 gi = cload2(&d_g2[e]),          gf = cload2(&d_g2[e + HD]);
      float2 gg = cload2(&d_g2[e + 2 * HD]), go = cload2(&d_g2[e + 3 * HD]);
      float2 rc = (t == 0) ? *(const float2*)(r3 + e) : cload2(&d_rec3[e]);
      float cA = sigf(gf.x) * s_c2[e]     + sigf(gi.x) * tanhfast(gg.x);
      float cB = sigf(gf.y) * s_c2[e + 1] + sigf(gi.y) * tanhfast(gg.y);
      float hA = sigf(go.x) * tanhfast(cA);
      float hB = sigf(go.y) * tanhfast(cB);
      s_c2[e] = cA; s_c2[e + 1] = cB;
      *(unsigned*)(s_h2 + e)  = packh2(hA, hB);
      *(unsigned*)(s_TD2 + e) = packh2(hA - rc.x, hB - rc.y);
    }
    if (tid < 64) {                     // softmax(z1(t)) -> predictions[t], TD0(t+1)
      float2 za = cload2(&d_z1[tid * 4]), zb = cload2(&d_z1[tid * 4 + 2]);
      float m = wredmax(fmaxf(fmaxf(za.x, za.y), fmaxf(zb.x, zb.y)));
      float e0 = __expf(za.x - m), e1 = __expf(za.y - m);
      float e2 = __expf(zb.x - m), e3 = __expf(zb.y - m);
      float inv = 1.f / wredsum((e0 + e1) + (e2 + e3));
      float p0 = e0 * inv, p1 = e1 * inv, p2 = e2 * inv, p3 = e3 * inv;
      if (t < TT - 1) {
        float4 xv = *(const float4*)(x + (size_t)(t + 1) * CD + tid * 4);
        *(uint2*)(s_small + tid * 4) =
            make_uint2(packh2(xv.x - p0, xv.y - p1), packh2(xv.z - p2, xv.w - p3));
        if (iswg0) {                    // loss0(t+1)
          float u = xv.x * __logf(p0) + (1.f - xv.x) * __logf(1.f - p0)
                  + xv.y * __logf(p1) + (1.f - xv.y) * __logf(1.f - p1)
                  + xv.z * __logf(p2) + (1.f - xv.z) * __logf(1.f - p2)
                  + xv.w * __logf(p3) + (1.f - xv.w) * __logf(1.f - p3);
          u = wredsum(u);
          if (tid == 0) { loss_acc -= u; fll_acc -= u; }
        }
      }
      if (iswg0) {                      // predictions[t]
        float* po = out + 2 + (size_t)t * CD + tid * 4;
        po[0] = p0; po[1] = p1; po[2] = p2; po[3] = p3;
      }
    }
    __syncthreads();
    if (w0) {                           // LAM^2 * sum|TD2(t)|
      float a = 0.f;
      #pragma unroll
      for (int k = 0; k < 16; ++k) a += fabsf(h2f(s_TD2[tid + 64 * k]));
      a = wredsum(a);
      if (tid == 0) loss_acc += (LAMF * LAMF) * a;
    }
    if (t < TT - 1) {
      {                                 // g3(t)
        float s = dotH(hM3   + (size_t)wid * HD, s_TD2, lane)
                + dotH(hWhh3 + (size_t)wid * HD, s_h3,  lane);
        s = wredsum(s);
        if (lane == 0) cstore(&d_g3[wid], s + b3);
      }
      {                                 // g1(t+1)
        float s = dotH256(hM1 + (size_t)wid * CD, s_small, lane)
                + dotH(hW1b  + (size_t)wid * HD, s_TD1, lane)
                + dotH(hWhh1 + (size_t)wid * HD, s_h1,  lane);
        s = wredsum(s);
        if (lane == 0) cstore(&d_g1[wid], s + b1);
      }
      if (jR >= 0) {                    // rec2(t) = Vw2 @ h2(t)
        float s = wredsum(dotH(hVw2 + (size_t)jR * HD, s_h2, lane));
        if (lane == 0) cstore(&d_rec2[jR], s + vbR2);
      }
      gbar(ep);
    }
  }

  if (iswg0 && tid == 0) { out[0] = loss_acc; out[1] = fll_acc; }
}

extern "C" void kernel_launch(void* const* d_in, const int* in_sizes, int n_in,
                              void* d_out, int out_size, void* d_ws, size_t ws_size,
                              hipStream_t stream) {
  const float* x    = (const float*)d_in[0];
  const float* Wih1 = (const float*)d_in[1];
  const float* Whh1 = (const float*)d_in[2];
  const float* bih1 = (const float*)d_in[3];
  const float* bhh1 = (const float*)d_in[4];
  const float* Vw1  = (const float*)d_in[5];
  const float* Vb1  = (const float*)d_in[6];
  const float* Wih2 = (const float*)d_in[7];
  const float* Whh2 = (const float*)d_in[8];
  const float* bih2 = (const float*)d_in[9];
  const float* bhh2 = (const float*)d_in[10];
  const float* Vw2  = (const float*)d_in[11];
  const float* Vb2  = (const float*)d_in[12];
  const float* Wih3 = (const float*)d_in[13];
  const float* Whh3 = (const float*)d_in[14];
  const float* bih3 = (const float*)d_in[15];
  const float* bhh3 = (const float*)d_in[16];
  const float* Vw3  = (const float*)d_in[17];
  const float* Vb3  = (const float*)d_in[18];
  const float* Ww0  = (const float*)d_in[19];
  const float* Wb0  = (const float*)d_in[20];
  const float* Ww1  = (const float*)d_in[21];
  const float* Wb1  = (const float*)d_in[22];
  const float* Ww2  = (const float*)d_in[23];
  const float* Wb2  = (const float*)d_in[24];
  const float* r1   = (const float*)d_in[25];
  const float* r2   = (const float*)d_in[26];
  const float* r3   = (const float*)d_in[27];

  pc_conv<<<1024, 256, 0, stream>>>(Wih1, Whh1, Wih2, Whh2, Whh3, Vw1, Vw2, Vw3);
  pc_fold<<<2304, 256, 0, stream>>>(Wih1, Wih2, Wih3, Ww0, Ww1, Ww2);
  pc_init<<<1, NWG, 0, stream>>>();
  pc_main<<<NWG, NTH, 0, stream>>>(x, Wih1, Whh1, bih1, bhh1, Vw1, Vb1,
                                   Wih2, Whh2, bih2, bhh2, Vw2, Vb2,
                                   Wih3, Whh3, bih3, bhh3, Vw3, Vb3,
                                   Ww0, Wb0, Ww1, Wb1, Ww2, Wb2,
                                   r1, r2, r3, (float*)d_out);
}